// Round 16
// baseline (776.507 us; speedup 1.0000x reference)
//
#include <hip/hip_runtime.h>
#include <hip/hip_bf16.h>
#include <cstddef>

// Problem dims
#define TT 256
#define BB 64
#define NN 77
#define DD 512
#define SS 334            // T + N + 1
#define HH 8
#define M1 (SS*BB)        // 21376
#define M2 (BB*TT)        // 16384
#define FF 2048

// Workspace: 3 regions of 10,944,512 floats each (125.25 MiB, proven OK).
#define REG 10944512ULL

typedef __attribute__((ext_vector_type(4))) float f32x4;
typedef __attribute__((ext_vector_type(8))) short bf16x8;
typedef __attribute__((ext_vector_type(8))) unsigned short u16x8;

__device__ inline unsigned short f2bf(float f) {
  __hip_bfloat16 h = __float2bfloat16(f);
  return *reinterpret_cast<unsigned short*>(&h);
}
__device__ inline float bf2f(unsigned short u) {
  return __uint_as_float(((unsigned)u) << 16);
}

// ---------------- batched f32 -> bf16 weight converter -----------------
__global__ __launch_bounds__(256) void cvt4_kernel(
    const float* s0, unsigned short* d0, int n0,
    const float* s1, unsigned short* d1, int n1,
    const float* s2, unsigned short* d2, int n2,
    const float* s3, unsigned short* d3, int n3) {
  const float* s; unsigned short* d; int n;
  switch (blockIdx.y) {
    case 0: s = s0; d = d0; n = n0; break;
    case 1: s = s1; d = d1; n = n1; break;
    case 2: s = s2; d = d2; n = n2; break;
    default: s = s3; d = d3; n = n3; break;
  }
  for (int i = (blockIdx.x * 256 + threadIdx.x) * 4; i < n; i += gridDim.x * 1024) {
    float4 v = *(const float4*)(s + i);
    ushort4 u;
    u.x = f2bf(v.x); u.y = f2bf(v.y); u.z = f2bf(v.z); u.w = f2bf(v.w);
    *(ushort4*)(d + i) = u;
  }
}

// ---------------- concat [x; xf; emb] -> src f32 + bf16 ----------------
__global__ __launch_bounds__(256) void concat_src_kernel(
    const float* __restrict__ x, const float* __restrict__ xf,
    const float* __restrict__ emb, float* __restrict__ src,
    unsigned short* __restrict__ srcbf) {
  int idx = blockIdx.x * 256 + threadIdx.x;      // float4 index
  if (idx >= SS * BB * 128) return;
  int c4 = idx & 127;
  int row = idx >> 7;                            // s*BB + b
  int s = row >> 6, b = row & 63;
  const float* p;
  if (s < TT)            p = x   + ((size_t)(s * BB + b)) * DD;
  else if (s < TT + NN)  p = xf  + ((size_t)((s - TT) * BB + b)) * DD;
  else                   p = emb + (size_t)b * DD;
  float4 v = ((const float4*)p)[c4];
  ((float4*)(src + (size_t)row * DD))[c4] = v;
  ushort4 u;
  u.x = f2bf(v.x); u.y = f2bf(v.y); u.z = f2bf(v.z); u.w = f2bf(v.w);
  ((ushort4*)(srcbf + (size_t)row * DD))[c4] = u;
}

// ---------------- MFMA GEMM (all-bf16, reg-staged, BK=64) --------------
// C = epi(A[M,K]bf16 @ W[N,K]bf16^T + bias); 128x128 tile, 4 waves.
// ldw = W row stride (2048 for ff_l2 column slices).
// EPI: 0 none, 1 relu, 2 gelu, 3 add-into-C(f32),
//      4 add-into-C(f32, T-MAJOR) + write bf16 copy (row-major) to C2,
//      5 out = Cp(f32 T-MAJOR read) + v, write f32 to C2 at (t*BB+b)*512+col,
//      6 fused per-64-col (head) softmax -> bf16 HEAD-MAJOR out,
//      7 scale by 0.125 then bf16 out,
//      8 add-into-C(f32, row-major), NO bias.
template<int EPI, bool CBF>
__global__ __launch_bounds__(256) void gemm_bf(
    const unsigned short* __restrict__ A, const unsigned short* __restrict__ W,
    const float* __restrict__ bias, void* __restrict__ Cp_, void* __restrict__ C2,
    int M, int K, int ldw, int ldc) {
  __shared__ unsigned short As[8][128][8];   // [k-chunk][row][k8]
  __shared__ unsigned short Bs[8][128][8];
  const int tid = threadIdx.x;
  // XCD swizzle
  int bxt, byt;
  {
    int total = gridDim.x * gridDim.y;
    int raw = blockIdx.y * gridDim.x + blockIdx.x;
    if ((total & 7) == 0) {
      int lid = (raw & 7) * (total >> 3) + (raw >> 3);
      bxt = lid % gridDim.x;
      byt = lid / gridDim.x;
    } else { bxt = blockIdx.x; byt = blockIdx.y; }
  }
  const int bm = byt * 128;
  const int bn = bxt * 128;
  const int lane = tid & 63;
  const int wave = tid >> 6;
  const int wr = wave >> 1, wc = wave & 1;
  const int q = lane >> 4, lr = lane & 15;

  f32x4 acc[4][4];
#pragma unroll
  for (int m = 0; m < 4; ++m)
#pragma unroll
    for (int n = 0; n < 4; ++n) acc[m][n] = (f32x4){0.f, 0.f, 0.f, 0.f};

  const int srow = tid >> 1;
  const int sk = (tid & 1) * 32;
  const int c0 = (tid & 1) * 4;
  int arow = bm + srow; if (arow >= M) arow = M - 1;
  const unsigned short* Ag = A + (size_t)arow * K + sk;
  const unsigned short* Wg = W + (size_t)(bn + srow) * ldw + sk;

  for (int k0 = 0; k0 < K; k0 += 64) {
    u16x8 a0 = *(const u16x8*)(Ag + k0);
    u16x8 a1 = *(const u16x8*)(Ag + k0 + 8);
    u16x8 a2 = *(const u16x8*)(Ag + k0 + 16);
    u16x8 a3 = *(const u16x8*)(Ag + k0 + 24);
    u16x8 b0 = *(const u16x8*)(Wg + k0);
    u16x8 b1 = *(const u16x8*)(Wg + k0 + 8);
    u16x8 b2 = *(const u16x8*)(Wg + k0 + 16);
    u16x8 b3 = *(const u16x8*)(Wg + k0 + 24);
    __syncthreads();
    *(u16x8*)&As[c0 + 0][srow][0] = a0;
    *(u16x8*)&As[c0 + 1][srow][0] = a1;
    *(u16x8*)&As[c0 + 2][srow][0] = a2;
    *(u16x8*)&As[c0 + 3][srow][0] = a3;
    *(u16x8*)&Bs[c0 + 0][srow][0] = b0;
    *(u16x8*)&Bs[c0 + 1][srow][0] = b1;
    *(u16x8*)&Bs[c0 + 2][srow][0] = b2;
    *(u16x8*)&Bs[c0 + 3][srow][0] = b3;
    __syncthreads();
#pragma unroll
    for (int ks = 0; ks < 2; ++ks) {
      bf16x8 af[4], bf[4];
#pragma unroll
      for (int m = 0; m < 4; ++m)
        af[m] = *(const bf16x8*)&As[ks * 4 + q][wr * 64 + m * 16 + lr][0];
#pragma unroll
      for (int n = 0; n < 4; ++n)
        bf[n] = *(const bf16x8*)&Bs[ks * 4 + q][wc * 64 + n * 16 + lr][0];
#pragma unroll
      for (int m = 0; m < 4; ++m)
#pragma unroll
        for (int n = 0; n < 4; ++n)
          acc[m][n] = __builtin_amdgcn_mfma_f32_16x16x32_bf16(af[m], bf[n], acc[m][n], 0, 0, 0);
    }
  }

  if (EPI == 6) {
    const int hcol = (bn >> 6) + wc;     // head of this wave's 64-col span
#pragma unroll
    for (int m = 0; m < 4; ++m) {
#pragma unroll
      for (int i = 0; i < 4; ++i) {
        float vv[4];
        float mx = -1e30f;
#pragma unroll
        for (int n = 0; n < 4; ++n) {
          float v = acc[m][n][i] + bias[bn + wc * 64 + n * 16 + lr];
          vv[n] = v; mx = fmaxf(mx, v);
        }
#pragma unroll
        for (int off = 8; off; off >>= 1) mx = fmaxf(mx, __shfl_xor(mx, off));
        float sum = 0.f;
#pragma unroll
        for (int n = 0; n < 4; ++n) { vv[n] = __expf(vv[n] - mx); sum += vv[n]; }
#pragma unroll
        for (int off = 8; off; off >>= 1) sum += __shfl_xor(sum, off);
        float inv = 1.f / sum;
        const int row = bm + wr * 64 + m * 16 + q * 4 + i;
        const int t = row & 255, b2 = row >> 8;
        unsigned short* dst =
            (unsigned short*)Cp_ + (((size_t)(b2 * 8 + hcol) * 256 + t) << 6);
#pragma unroll
        for (int n = 0; n < 4; ++n)
          dst[n * 16 + lr] = f2bf(vv[n] * inv);
      }
    }
    return;
  }

#pragma unroll
  for (int m = 0; m < 4; ++m) {
#pragma unroll
    for (int n = 0; n < 4; ++n) {
      const int col = bn + wc * 64 + n * 16 + lr;
      const float bb = (EPI == 8) ? 0.f : bias[col];
#pragma unroll
      for (int i = 0; i < 4; ++i) {
        const int row = bm + wr * 64 + m * 16 + q * 4 + i;
        if (row < M) {
          float v = acc[m][n][i] + bb;
          if (EPI == 1) v = fmaxf(v, 0.f);
          if (EPI == 2) v = 0.5f * v * (1.f + erff(v * 0.70710678118f));
          if (EPI == 7) v *= 0.125f;
          if (EPI <= 2 || EPI == 7) {
            if (CBF) ((unsigned short*)Cp_)[(size_t)row * ldc + col] = f2bf(v);
            else     ((float*)Cp_)[(size_t)row * ldc + col] = v;
          } else if (EPI == 3 || EPI == 8) {
            ((float*)Cp_)[(size_t)row * ldc + col] += v;
          } else if (EPI == 4) {
            const int t = row & 255, b2 = row >> 8;
            float* C = (float*)Cp_ + ((size_t)(t * BB + b2)) * DD + col;
            float o = *C + v; *C = o;
            ((unsigned short*)C2)[(size_t)row * ldc + col] = f2bf(o);
          } else {  // EPI == 5
            const int t = row & 255, b2 = row >> 8;
            const size_t idx = ((size_t)(t * BB + b2)) * DD + col;
            float o = ((const float*)Cp_)[idx] + v;
            ((float*)C2)[idx] = o;
          }
        }
      }
    }
  }
}

// ------- WIDE MFMA GEMM: 128x256 tile, 4 waves (64x128 each), BK=64 ----
// For N-heavy GEMMs (N multiple of 256, M multiple of 128). bf16 out only.
// EPI: 0 none, 1 relu, 2 gelu.
template<int EPI>
__global__ __launch_bounds__(256) void gemm_bf_wide(
    const unsigned short* __restrict__ A, const unsigned short* __restrict__ W,
    const float* __restrict__ bias, unsigned short* __restrict__ Cp,
    int M, int K, int ldw, int ldc) {
  __shared__ unsigned short As[8][128][8];   // 16 KB
  __shared__ unsigned short Bs[8][256][8];   // 32 KB
  const int tid = threadIdx.x;
  const int bm = blockIdx.y * 128;
  const int bn = blockIdx.x * 256;
  const int lane = tid & 63;
  const int wave = tid >> 6;
  const int wr = wave >> 1, wc = wave & 1;   // wave: rows wr*64, cols wc*128
  const int q = lane >> 4, lr = lane & 15;

  f32x4 acc[4][8];
#pragma unroll
  for (int m = 0; m < 4; ++m)
#pragma unroll
    for (int n = 0; n < 8; ++n) acc[m][n] = (f32x4){0.f, 0.f, 0.f, 0.f};

  // A staging: row tid>>1, k-offset (tid&1)*32 (4 chunks)
  const int srow = tid >> 1;
  const int sk = (tid & 1) * 32;
  const int c0 = (tid & 1) * 4;
  int arow = bm + srow; if (arow >= M) arow = M - 1;
  const unsigned short* Ag = A + (size_t)arow * K + sk;
  // B staging: row tid, all 8 chunks
  const unsigned short* Wg = W + (size_t)(bn + tid) * ldw;

  for (int k0 = 0; k0 < K; k0 += 64) {
    u16x8 a0 = *(const u16x8*)(Ag + k0);
    u16x8 a1 = *(const u16x8*)(Ag + k0 + 8);
    u16x8 a2 = *(const u16x8*)(Ag + k0 + 16);
    u16x8 a3 = *(const u16x8*)(Ag + k0 + 24);
    u16x8 b0 = *(const u16x8*)(Wg + k0);
    u16x8 b1 = *(const u16x8*)(Wg + k0 + 8);
    u16x8 b2 = *(const u16x8*)(Wg + k0 + 16);
    u16x8 b3 = *(const u16x8*)(Wg + k0 + 24);
    u16x8 b4 = *(const u16x8*)(Wg + k0 + 32);
    u16x8 b5 = *(const u16x8*)(Wg + k0 + 40);
    u16x8 b6 = *(const u16x8*)(Wg + k0 + 48);
    u16x8 b7 = *(const u16x8*)(Wg + k0 + 56);
    __syncthreads();
    *(u16x8*)&As[c0 + 0][srow][0] = a0;
    *(u16x8*)&As[c0 + 1][srow][0] = a1;
    *(u16x8*)&As[c0 + 2][srow][0] = a2;
    *(u16x8*)&As[c0 + 3][srow][0] = a3;
    *(u16x8*)&Bs[0][tid][0] = b0;
    *(u16x8*)&Bs[1][tid][0] = b1;
    *(u16x8*)&Bs[2][tid][0] = b2;
    *(u16x8*)&Bs[3][tid][0] = b3;
    *(u16x8*)&Bs[4][tid][0] = b4;
    *(u16x8*)&Bs[5][tid][0] = b5;
    *(u16x8*)&Bs[6][tid][0] = b6;
    *(u16x8*)&Bs[7][tid][0] = b7;
    __syncthreads();
#pragma unroll
    for (int ks = 0; ks < 2; ++ks) {
      bf16x8 af[4], bf[8];
#pragma unroll
      for (int m = 0; m < 4; ++m)
        af[m] = *(const bf16x8*)&As[ks * 4 + q][wr * 64 + m * 16 + lr][0];
#pragma unroll
      for (int n = 0; n < 8; ++n)
        bf[n] = *(const bf16x8*)&Bs[ks * 4 + q][wc * 128 + n * 16 + lr][0];
#pragma unroll
      for (int m = 0; m < 4; ++m)
#pragma unroll
        for (int n = 0; n < 8; ++n)
          acc[m][n] = __builtin_amdgcn_mfma_f32_16x16x32_bf16(af[m], bf[n], acc[m][n], 0, 0, 0);
    }
  }

#pragma unroll
  for (int m = 0; m < 4; ++m) {
#pragma unroll
    for (int n = 0; n < 8; ++n) {
      const int col = bn + wc * 128 + n * 16 + lr;
      const float bb = bias[col];
#pragma unroll
      for (int i = 0; i < 4; ++i) {
        const int row = bm + wr * 64 + m * 16 + q * 4 + i;
        if (row < M) {
          float v = acc[m][n][i] + bb;
          if (EPI == 1) v = fmaxf(v, 0.f);
          if (EPI == 2) v = 0.5f * v * (1.f + erff(v * 0.70710678118f));
          Cp[(size_t)row * ldc + col] = f2bf(v);
        }
      }
    }
  }
}

// ---------------- MFMA flash attention: 128 queries per block ----------
__global__ __launch_bounds__(256) void attn_mfma_kernel(
    const unsigned short* __restrict__ Qb, const unsigned short* __restrict__ KVb,
    unsigned short* __restrict__ Ob) {
  __shared__ unsigned short Qs[128][72];
  __shared__ unsigned short Ks[64][72];
  __shared__ unsigned short Vt[64][72];
  __shared__ unsigned short Ps[4][16][72];
  const int bh = blockIdx.y, b = bh >> 3, h = bh & 7;
  const int s0 = blockIdx.x << 7;
  const int tid = threadIdx.x;
  const int wave = tid >> 6, lane = tid & 63;
  const int q = lane >> 4, lr = lane & 15;
  const int sr = tid >> 2;
  const int c0 = (tid & 3) << 4;
#pragma unroll
  for (int it = 0; it < 4; ++it) {
    int v = it * 256 + tid;
    int row = v >> 3, col = (v & 7) * 8;
    u16x8 d8 = *(const u16x8*)(Qb + ((size_t)((s0 + row) * BB + b)) * 512 + h * 64 + col);
    *(u16x8*)&Qs[row][col] = d8;
  }
  f32x4 oacc[2][4];
#pragma unroll
  for (int m = 0; m < 2; ++m)
#pragma unroll
    for (int dt = 0; dt < 4; ++dt) oacc[m][dt] = (f32x4){0.f, 0.f, 0.f, 0.f};
  float m_r[2][4], l_r[2][4];
#pragma unroll
  for (int m = 0; m < 2; ++m)
#pragma unroll
    for (int i = 0; i < 4; ++i) { m_r[m][i] = -1e30f; l_r[m][i] = 0.f; }

  for (int kt = 0; kt < 6; ++kt) {
    __syncthreads();
    {
      int t = kt * 64 + sr;
      u16x8 k0 = {0, 0, 0, 0, 0, 0, 0, 0}, k1 = k0, w0 = k0, w1 = k0;
      if (t < SS) {
        const unsigned short* kp = KVb + ((size_t)(t * BB + b)) * 1024 + h * 64 + c0;
        k0 = *(const u16x8*)kp; k1 = *(const u16x8*)(kp + 8);
        w0 = *(const u16x8*)(kp + 512); w1 = *(const u16x8*)(kp + 520);
      }
      *(u16x8*)&Ks[sr][c0] = k0;
      *(u16x8*)&Ks[sr][c0 + 8] = k1;
#pragma unroll
      for (int j = 0; j < 8; ++j) Vt[c0 + j][sr] = w0[j];
#pragma unroll
      for (int j = 0; j < 8; ++j) Vt[c0 + 8 + j][sr] = w1[j];
    }
    __syncthreads();
#pragma unroll
    for (int m = 0; m < 2; ++m) {
      f32x4 sacc[4];
#pragma unroll
      for (int ct = 0; ct < 4; ++ct) sacc[ct] = (f32x4){0.f, 0.f, 0.f, 0.f};
#pragma unroll
      for (int kc = 0; kc < 2; ++kc) {
        bf16x8 aq = *(const bf16x8*)&Qs[wave * 32 + m * 16 + lr][kc * 32 + q * 8];
#pragma unroll
        for (int ct = 0; ct < 4; ++ct) {
          bf16x8 bk = *(const bf16x8*)&Ks[ct * 16 + lr][kc * 32 + q * 8];
          sacc[ct] = __builtin_amdgcn_mfma_f32_16x16x32_bf16(aq, bk, sacc[ct], 0, 0, 0);
        }
      }
      if (kt == 5) {
#pragma unroll
        for (int ct = 0; ct < 4; ++ct)
          if (320 + ct * 16 + lr >= SS) {
#pragma unroll
            for (int i = 0; i < 4; ++i) sacc[ct][i] = -1e30f;
          }
      }
      float pexp[4][4];
#pragma unroll
      for (int i = 0; i < 4; ++i) {
        float mt = fmaxf(fmaxf(sacc[0][i], sacc[1][i]), fmaxf(sacc[2][i], sacc[3][i]));
#pragma unroll
        for (int off = 8; off; off >>= 1) mt = fmaxf(mt, __shfl_xor(mt, off));
        float mn = fmaxf(m_r[m][i], mt);
        float rescale = __expf(m_r[m][i] - mn);
        m_r[m][i] = mn;
        float se = 0.f;
#pragma unroll
        for (int ct = 0; ct < 4; ++ct) {
          float e = __expf(sacc[ct][i] - mn);
          pexp[ct][i] = e;
          se += e;
        }
#pragma unroll
        for (int off = 8; off; off >>= 1) se += __shfl_xor(se, off);
        l_r[m][i] = l_r[m][i] * rescale + se;
#pragma unroll
        for (int dt = 0; dt < 4; ++dt) oacc[m][dt][i] *= rescale;
      }
#pragma unroll
      for (int ct = 0; ct < 4; ++ct)
#pragma unroll
        for (int i = 0; i < 4; ++i)
          Ps[wave][q * 4 + i][ct * 16 + lr] = f2bf(pexp[ct][i]);
#pragma unroll
      for (int kc = 0; kc < 2; ++kc) {
        bf16x8 ap = *(const bf16x8*)&Ps[wave][lr][kc * 32 + q * 8];
#pragma unroll
        for (int dt = 0; dt < 4; ++dt) {
          bf16x8 bv = *(const bf16x8*)&Vt[dt * 16 + lr][kc * 32 + q * 8];
          oacc[m][dt] = __builtin_amdgcn_mfma_f32_16x16x32_bf16(ap, bv, oacc[m][dt], 0, 0, 0);
        }
      }
    }
  }
#pragma unroll
  for (int m = 0; m < 2; ++m) {
#pragma unroll
    for (int i = 0; i < 4; ++i) {
      int s = s0 + wave * 32 + m * 16 + q * 4 + i;
      float inv = 1.f / l_r[m][i];
      unsigned short* op = Ob + ((size_t)(s * BB + b)) * 512 + h * 64;
#pragma unroll
      for (int dt = 0; dt < 4; ++dt)
        op[dt * 16 + lr] = f2bf(oacc[m][dt][i] * inv);
    }
  }
}

// ------- MFMA linear-attn PV -------------------------------------------
__global__ __launch_bounds__(256) void lin_y_mfma(
    const unsigned short* __restrict__ qch, const unsigned short* __restrict__ ctxT,
    float* __restrict__ y) {
  __shared__ unsigned short Qs[256][72];
  __shared__ unsigned short Cs[64][72];
  const int bh = blockIdx.x, b = bh >> 3, h = bh & 7;
  const int tid = threadIdx.x;
  const int wave = tid >> 6, lane = tid & 63;
  const int q = lane >> 4, lr = lane & 15;
  {
    const unsigned short* qp = qch + (size_t)bh * 16384;
#pragma unroll
    for (int it = 0; it < 8; ++it) {
      int v = it * 256 + tid;
      u16x8 d8 = *(const u16x8*)(qp + v * 8);
      *(u16x8*)&Qs[v >> 3][(v & 7) * 8] = d8;
    }
    const unsigned short* cp = ctxT + (size_t)bh * 4096;
#pragma unroll
    for (int it = 0; it < 2; ++it) {
      int v = it * 256 + tid;
      u16x8 d8 = *(const u16x8*)(cp + v * 8);
      *(u16x8*)&Cs[v >> 3][(v & 7) * 8] = d8;
    }
  }
  __syncthreads();
  f32x4 acc[4][4];
#pragma unroll
  for (int m = 0; m < 4; ++m)
#pragma unroll
    for (int n = 0; n < 4; ++n) acc[m][n] = (f32x4){0.f, 0.f, 0.f, 0.f};
#pragma unroll
  for (int kc = 0; kc < 2; ++kc) {
    bf16x8 af[4], bf[4];
#pragma unroll
    for (int m = 0; m < 4; ++m)
      af[m] = *(const bf16x8*)&Qs[wave * 64 + m * 16 + lr][kc * 32 + q * 8];
#pragma unroll
    for (int n = 0; n < 4; ++n)
      bf[n] = *(const bf16x8*)&Cs[n * 16 + lr][kc * 32 + q * 8];
#pragma unroll
    for (int m = 0; m < 4; ++m)
#pragma unroll
      for (int n = 0; n < 4; ++n)
        acc[m][n] = __builtin_amdgcn_mfma_f32_16x16x32_bf16(af[m], bf[n], acc[m][n], 0, 0, 0);
  }
#pragma unroll
  for (int m = 0; m < 4; ++m) {
#pragma unroll
    for (int n = 0; n < 4; ++n) {
#pragma unroll
      for (int i = 0; i < 4; ++i) {
        int t = wave * 64 + m * 16 + q * 4 + i;
        y[((size_t)(b * TT + t)) * DD + h * 64 + n * 16 + lr] = acc[m][n][i];
      }
    }
  }
}

// ------- fused silu + both stylization emb linears (eo, eo2) -----------
__global__ __launch_bounds__(256) void gemm_se_kernel(
    const float* __restrict__ emb,
    const float* __restrict__ w0, const float* __restrict__ b0, float* __restrict__ c0_,
    const float* __restrict__ w1, const float* __restrict__ b1, float* __restrict__ c1_) {
  __shared__ float As[16][64];
  __shared__ float Ws[16][64];
  const float* W    = blockIdx.y ? w1 : w0;
  const float* bias = blockIdx.y ? b1 : b0;
  float* C          = blockIdx.y ? c1_ : c0_;
  const int tid = threadIdx.x;
  const int bn = blockIdx.x << 6;
  const int lr = tid >> 2;
  const int lk = (tid & 3) << 2;
  const float* Ap = emb + (size_t)lr * 512 + lk;
  const float* Wp = W + (size_t)(bn + lr) * 512 + lk;
  const int tx = tid & 15, ty = tid >> 4;
  float c[4][4] = {};
  for (int k0 = 0; k0 < 512; k0 += 16) {
    float4 av = *(const float4*)(Ap + k0);
    av.x = av.x / (1.f + __expf(-av.x));
    av.y = av.y / (1.f + __expf(-av.y));
    av.z = av.z / (1.f + __expf(-av.z));
    av.w = av.w / (1.f + __expf(-av.w));
    float4 wv = *(const float4*)(Wp + k0);
    __syncthreads();
    As[lk + 0][lr] = av.x; As[lk + 1][lr] = av.y;
    As[lk + 2][lr] = av.z; As[lk + 3][lr] = av.w;
    Ws[lk + 0][lr] = wv.x; Ws[lk + 1][lr] = wv.y;
    Ws[lk + 2][lr] = wv.z; Ws[lk + 3][lr] = wv.w;
    __syncthreads();
#pragma unroll
    for (int k = 0; k < 16; ++k) {
      const float4 a = *(const float4*)&As[k][ty << 2];
      const float4 w = *(const float4*)&Ws[k][tx << 2];
      c[0][0] += a.x * w.x; c[0][1] += a.x * w.y; c[0][2] += a.x * w.z; c[0][3] += a.x * w.w;
      c[1][0] += a.y * w.x; c[1][1] += a.y * w.y; c[1][2] += a.y * w.z; c[1][3] += a.y * w.w;
      c[2][0] += a.z * w.x; c[2][1] += a.z * w.y; c[2][2] += a.z * w.z; c[2][3] += a.z * w.w;
      c[3][0] += a.w * w.x; c[3][1] += a.w * w.y; c[3][2] += a.w * w.z; c[3][3] += a.w * w.w;
    }
  }
#pragma unroll
  for (int i = 0; i < 4; ++i) {
    int row = (ty << 2) + i;
    float* Cp = C + (size_t)row * 1024 + bn + (tx << 2);
#pragma unroll
    for (int j = 0; j < 4; ++j)
      Cp[j] = c[i][j] + bias[bn + (tx << 2) + j];
  }
}

// ---------------- LayerNorm row kernel: f32 out + optional bf16 out ----
__global__ __launch_bounds__(64) void ln_kernel(
    const float* __restrict__ in, const float* __restrict__ res,
    float* __restrict__ out, const float* __restrict__ g,
    const float* __restrict__ beta, unsigned short* __restrict__ obf) {
  const int row = blockIdx.x;
  const int lane = threadIdx.x;
  const float* ip = in + (size_t)row * DD;
  float v[8];
  float s = 0.f, ss = 0.f;
#pragma unroll
  for (int u = 0; u < 2; ++u) {
    int d = u * 256 + lane * 4;
    float4 a = *(const float4*)(ip + d);
    if (res) {
      float4 r = *(const float4*)(res + (size_t)row * DD + d);
      a.x += r.x; a.y += r.y; a.z += r.z; a.w += r.w;
    }
    v[u * 4 + 0] = a.x; v[u * 4 + 1] = a.y; v[u * 4 + 2] = a.z; v[u * 4 + 3] = a.w;
    s += a.x + a.y + a.z + a.w;
    ss += a.x * a.x + a.y * a.y + a.z * a.z + a.w * a.w;
  }
#pragma unroll
  for (int off = 32; off; off >>= 1) { s += __shfl_xor(s, off); ss += __shfl_xor(ss, off); }
  float mean = s * (1.f / 512.f);
  float var = ss * (1.f / 512.f) - mean * mean;
  float rstd = rsqrtf(var + 1e-5f);
  float* op = out + (size_t)row * DD;
#pragma unroll
  for (int u = 0; u < 2; ++u) {
    int d = u * 256 + lane * 4;
    float4 o4;
    o4.x = (v[u * 4 + 0] - mean) * rstd * g[d + 0] + beta[d + 0];
    o4.y = (v[u * 4 + 1] - mean) * rstd * g[d + 1] + beta[d + 1];
    o4.z = (v[u * 4 + 2] - mean) * rstd * g[d + 2] + beta[d + 2];
    o4.w = (v[u * 4 + 3] - mean) * rstd * g[d + 3] + beta[d + 3];
    *(float4*)(op + d) = o4;
    if (obf) {
      ushort4 u4;
      u4.x = f2bf(o4.x); u4.y = f2bf(o4.y); u4.z = f2bf(o4.z); u4.w = f2bf(o4.w);
      *(ushort4*)(obf + (size_t)row * DD + d) = u4;
    }
  }
}

// ------- fused residual-LN (IN-PLACE, t-major) + second LN (bf16 out) --
__global__ __launch_bounds__(64) void t2bln_res_kernel(
    float* __restrict__ src, const float* __restrict__ proj2,
    unsigned short* __restrict__ xnbf,
    const float* __restrict__ g2, const float* __restrict__ b2,
    const float* __restrict__ gca, const float* __restrict__ bca) {
  const int row = blockIdx.x;          // t*BB + b
  const int t = row >> 6, b = row & 63;
  const size_t soff = (size_t)row * DD;
  const int lane = threadIdx.x;
  float v[8];
  float s = 0.f, ss = 0.f;
#pragma unroll
  for (int u = 0; u < 2; ++u) {
    int d = u * 256 + lane * 4;
    float4 a = *(const float4*)(src + soff + d);
    float4 r = *(const float4*)(proj2 + soff + d);
    a.x += r.x; a.y += r.y; a.z += r.z; a.w += r.w;
    v[u * 4 + 0] = a.x; v[u * 4 + 1] = a.y; v[u * 4 + 2] = a.z; v[u * 4 + 3] = a.w;
    s += a.x + a.y + a.z + a.w;
    ss += a.x * a.x + a.y * a.y + a.z * a.z + a.w * a.w;
  }
#pragma unroll
  for (int off = 32; off; off >>= 1) { s += __shfl_xor(s, off); ss += __shfl_xor(ss, off); }
  float mean = s * (1.f / 512.f);
  float var = ss * (1.f / 512.f) - mean * mean;
  float rstd = rsqrtf(var + 1e-5f);
  float s2 = 0.f, ss2 = 0.f;
#pragma unroll
  for (int u = 0; u < 8; ++u) {
    int d = (u >> 2) * 256 + lane * 4 + (u & 3);
    float o = (v[u] - mean) * rstd * g2[d] + b2[d];
    v[u] = o;
    s2 += o; ss2 += o * o;
  }
#pragma unroll
  for (int u = 0; u < 2; ++u) {
    int d = u * 256 + lane * 4;
    float4 o4 = {v[u * 4 + 0], v[u * 4 + 1], v[u * 4 + 2], v[u * 4 + 3]};
    *(float4*)(src + soff + d) = o4;
  }
#pragma unroll
  for (int off = 32; off; off >>= 1) { s2 += __shfl_xor(s2, off); ss2 += __shfl_xor(ss2, off); }
  float mean2 = s2 * (1.f / 512.f);
  float var2 = ss2 * (1.f / 512.f) - mean2 * mean2;
  float rstd2 = rsqrtf(var2 + 1e-5f);
  const size_t orow = (size_t)(b * TT + t) * DD;
#pragma unroll
  for (int u = 0; u < 2; ++u) {
    int d = u * 256 + lane * 4;
    ushort4 u4;
    u4.x = f2bf((v[u * 4 + 0] - mean2) * rstd2 * gca[d + 0] + bca[d + 0]);
    u4.y = f2bf((v[u * 4 + 1] - mean2) * rstd2 * gca[d + 1] + bca[d + 1]);
    u4.z = f2bf((v[u * 4 + 2] - mean2) * rstd2 * gca[d + 2] + bca[d + 2]);
    u4.w = f2bf((v[u * 4 + 3] - mean2) * rstd2 * gca[d + 3] + bca[d + 3]);
    *(ushort4*)(xnbf + orow + d) = u4;
  }
}

// ------- fused transpose + LN (xf path) --------------------------------
__global__ __launch_bounds__(64) void t2bln_kernel(
    const float* __restrict__ in, unsigned short* __restrict__ obf,
    const float* __restrict__ g, const float* __restrict__ beta, int Rr) {
  const int rp = blockIdx.x;
  const int b = rp / Rr, r = rp % Rr;
  const float* ip = in + ((size_t)(r * BB + b)) * DD;
  const int lane = threadIdx.x;
  float v[8];
  float s = 0.f, ss = 0.f;
#pragma unroll
  for (int u = 0; u < 2; ++u) {
    int d = u * 256 + lane * 4;
    float4 a = *(const float4*)(ip + d);
    v[u * 4 + 0] = a.x; v[u * 4 + 1] = a.y; v[u * 4 + 2] = a.z; v[u * 4 + 3] = a.w;
    s += a.x + a.y + a.z + a.w;
    ss += a.x * a.x + a.y * a.y + a.z * a.z + a.w * a.w;
  }
#pragma unroll
  for (int off = 32; off; off >>= 1) { s += __shfl_xor(s, off); ss += __shfl_xor(ss, off); }
  float mean = s * (1.f / 512.f);
  float var = ss * (1.f / 512.f) - mean * mean;
  float rstd = rsqrtf(var + 1e-5f);
#pragma unroll
  for (int u = 0; u < 2; ++u) {
    int d = u * 256 + lane * 4;
    ushort4 u4;
    u4.x = f2bf((v[u * 4 + 0] - mean) * rstd * g[d + 0] + beta[d + 0]);
    u4.y = f2bf((v[u * 4 + 1] - mean) * rstd * g[d + 1] + beta[d + 1]);
    u4.z = f2bf((v[u * 4 + 2] - mean) * rstd * g[d + 2] + beta[d + 2]);
    u4.w = f2bf((v[u * 4 + 3] - mean) * rstd * g[d + 3] + beta[d + 3]);
    *(ushort4*)(obf + (size_t)rp * DD + d) = u4;
  }
}

// ---------------- stylization: silu(LN(y)*(1+scale)+shift) -> bf16 -----
__global__ __launch_bounds__(64) void styl_kernel(
    const float* __restrict__ y, const float* __restrict__ eo,
    const float* __restrict__ g, const float* __restrict__ beta,
    unsigned short* __restrict__ out) {
  const int row = blockIdx.x;         // b*TT + t
  const int b = row >> 8;
  const int lane = threadIdx.x;
  const float* ip = y + (size_t)row * DD;
  const float* sc = eo + (size_t)b * 1024;
  float v[8];
  float s = 0.f, ss = 0.f;
#pragma unroll
  for (int u = 0; u < 2; ++u) {
    int d = u * 256 + lane * 4;
    float4 a = *(const float4*)(ip + d);
    v[u * 4 + 0] = a.x; v[u * 4 + 1] = a.y; v[u * 4 + 2] = a.z; v[u * 4 + 3] = a.w;
    s += a.x + a.y + a.z + a.w;
    ss += a.x * a.x + a.y * a.y + a.z * a.z + a.w * a.w;
  }
#pragma unroll
  for (int off = 32; off; off >>= 1) { s += __shfl_xor(s, off); ss += __shfl_xor(ss, off); }
  float mean = s * (1.f / 512.f);
  float var = ss * (1.f / 512.f) - mean * mean;
  float rstd = rsqrtf(var + 1e-5f);
#pragma unroll
  for (int u = 0; u < 2; ++u) {
    int d0 = u * 256 + lane * 4;
    ushort4 u4;
#pragma unroll
    for (int j = 0; j < 4; ++j) {
      int d = d0 + j;
      float ln = (v[u * 4 + j] - mean) * rstd * g[d] + beta[d];
      float h = ln * (1.f + sc[d]) + sc[512 + d];
      float r = h / (1.f + __expf(-h));
      ((unsigned short*)&u4)[j] = f2bf(r);
    }
    *(ushort4*)(out + (size_t)row * DD + d0) = u4;
  }
}

// ---------------- softmax over n (kc, axis=1, 77 tokens) ---------------
__global__ __launch_bounds__(256) void softmax_n_kernel(float* __restrict__ a) {
  int b = blockIdx.x;
  int c = blockIdx.y * 256 + threadIdx.x;
  float* p = a + ((size_t)b * NN) * DD + c;
  float m = -1e30f;
  for (int n = 0; n < NN; ++n) m = fmaxf(m, p[(size_t)n * DD]);
  float sum = 0.f;
  for (int n = 0; n < NN; ++n) sum += __expf(p[(size_t)n * DD] - m);
  float inv = 1.f / sum;
  for (int n = 0; n < NN; ++n) p[(size_t)n * DD] = __expf(p[(size_t)n * DD] - m) * inv;
}

// ------- ctx: ctxT[bh][l][d] (bf16) = sum_n kc[b,n,h,d]*vc[b,n,h,l] ----
__global__ __launch_bounds__(256) void ctx_kernel(
    const float* __restrict__ kc, const float* __restrict__ vc,
    unsigned short* __restrict__ ctxT) {
  __shared__ float ks[NN][64];
  __shared__ float vs[NN][64];
  int bh = blockIdx.x; int b = bh >> 3, h = bh & 7;
  for (int l = threadIdx.x; l < NN * 64; l += 256) {
    int n = l >> 6, d = l & 63;
    size_t idx = ((size_t)(b * NN + n)) * DD + h * 64 + d;
    ks[n][d] = kc[idx];
    vs[n][d] = vc[idx];
  }
  __syncthreads();
  int d = threadIdx.x >> 2;
  int l0 = (threadIdx.x & 3) << 4;
  float acc[16] = {};
  for (int n = 0; n < NN; ++n) {
    float kd = ks[n][d];
#pragma unroll
    for (int j = 0; j < 16; ++j) acc[j] += kd * vs[n][l0 + j];
  }
  unsigned short* cp = ctxT + (size_t)bh * 4096 + d;
#pragma unroll
  for (int j = 0; j < 16; ++j) cp[(size_t)(l0 + j) * 64] = f2bf(acc[j]);
}

extern "C" void kernel_launch(void* const* d_in, const int* in_sizes, int n_in,
                              void* d_out, int out_size, void* d_ws, size_t ws_size,
                              hipStream_t stream) {
  const float* x       = (const float*)d_in[0];
  const float* xf      = (const float*)d_in[1];
  const float* emb     = (const float*)d_in[2];
  const float* sa_in_w = (const float*)d_in[3];
  const float* sa_in_b = (const float*)d_in[4];
  const float* sa_out_w= (const float*)d_in[5];
  const float* sa_out_b= (const float*)d_in[6];
  const float* sa_l1_w = (const float*)d_in[7];
  const float* sa_l1_b = (const float*)d_in[8];
  const float* sa_l2_w = (const float*)d_in[9];
  const float* sa_l2_b = (const float*)d_in[10];
  const float* sa_n1_g = (const float*)d_in[11];
  const float* sa_n1_b = (const float*)d_in[12];
  const float* sa_n2_g = (const float*)d_in[13];
  const float* sa_n2_b = (const float*)d_in[14];
  const float* ca_norm_g = (const float*)d_in[15];
  const float* ca_norm_b = (const float*)d_in[16];
  const float* ca_tnorm_g= (const float*)d_in[17];
  const float* ca_tnorm_b= (const float*)d_in[18];
  const float* ca_q_w  = (const float*)d_in[19];
  const float* ca_q_b  = (const float*)d_in[20];
  const float* ca_k_w  = (const float*)d_in[21];
  const float* ca_k_b  = (const float*)d_in[22];
  const float* ca_v_w  = (const float*)d_in[23];
  const float* ca_v_b  = (const float*)d_in[24];
  const float* ca_se_w = (const float*)d_in[25];
  const float* ca_se_b = (const float*)d_in[26];
  const float* ca_sn_g = (const float*)d_in[27];
  const float* ca_sn_b = (const float*)d_in[28];
  const float* ca_so_w = (const float*)d_in[29];
  const float* ca_so_b = (const float*)d_in[30];
  const float* ff_l1_w = (const float*)d_in[31];
  const float* ff_l1_b = (const float*)d_in[32];
  const float* ff_l2_w = (const float*)d_in[33];
  const float* ff_l2_b = (const float*)d_in[34];
  const float* ff_se_w = (const float*)d_in[35];
  const float* ff_se_b = (const float*)d_in[36];
  const float* ff_sn_g = (const float*)d_in[37];
  const float* ff_sn_b = (const float*)d_in[38];
  const float* ff_so_w = (const float*)d_in[39];
  const float* ff_so_b = (const float*)d_in[40];

  float* R1 = (float*)d_ws;
  float* R2 = R1 + REG;
  float* R3 = R2 + REG;
  float* dof = (float*)d_out;

  // bf16 weight slots
  unsigned short* w_sa_in  = (unsigned short*)dof;
  unsigned short* w_sa_out = w_sa_in + 786432;
  unsigned short* w_sa_l1  = w_sa_out + 262144;
  unsigned short* w_sa_l2  = w_sa_l1 + 524288;
  unsigned short* srcbf    = (unsigned short*)(dof + 1048576);
  unsigned short* w_ca_q  = (unsigned short*)(R2 + 8552448);
  unsigned short* w_ca_k  = w_ca_q + 262144;
  unsigned short* w_ca_v  = w_ca_k + 262144;
  unsigned short* w_ca_so = w_ca_v + 262144;
  unsigned short* w_ff_l1 = (unsigned short*)(R2 + 9076736);
  unsigned short* w_ff_l2 = w_ff_l1 + 1048576;
  unsigned short* w_ff_so = w_ff_l2 + 1048576;

  // Phase A aliases
  float* src = R1;
  unsigned short* Qbf  = (unsigned short*)R3;
  unsigned short* Obf  = (unsigned short*)(R3 + 5472256);
  unsigned short* KVbf = (unsigned short*)R2;
  float* proj  = R2;
  unsigned short* h1bf = (unsigned short*)R2;
  float* proj2 = R3;
  float* xbt = R1;
  // Phase B aliases
  unsigned short* xnbf = (unsigned short*)R2;
  unsigned short* tnbf = (unsigned short*)(R2 + 4194304);
  unsigned short* qch = (unsigned short*)dof;
  float* kc  = R3;
  float* vc  = R3 + 2523136;
  unsigned short* ctxTbf = (unsigned short*)(R3 + 5046272);
  unsigned short* hstbf = (unsigned short*)(R3 + 6094848);
  unsigned short* xbbf  = (unsigned short*)(R3 + 8192000);
  float* eo  = R2 + 8421376;
  float* eo2 = eo + 65536;
  float* yb  = R2;
  // Phase C aliases
  unsigned short* g1bf = (unsigned short*)R2;
  float* y2 = dof;
  unsigned short* hst2bf = (unsigned short*)R3;

  // ---------- Phase A ----------
  cvt4_kernel<<<dim3(1024, 4), 256, 0, stream>>>(
      sa_in_w, w_sa_in, 786432, sa_out_w, w_sa_out, 262144,
      sa_l1_w, w_sa_l1, 524288, sa_l2_w, w_sa_l2, 524288);
  concat_src_kernel<<<10688, 256, 0, stream>>>(x, xf, emb, src, srcbf);
  gemm_bf<7, true><<<dim3(4, 128), 256, 0, stream>>>(
      srcbf, w_sa_in, sa_in_b, Qbf, nullptr, M2, 512, 512, 512);
  gemm_bf_wide<0><<<dim3(4, 167), 256, 0, stream>>>(
      srcbf, w_sa_in + (size_t)512 * 512, sa_in_b + 512, KVbf, M1, 512, 512, 1024);
  attn_mfma_kernel<<<dim3(2, BB * HH), 256, 0, stream>>>(Qbf, KVbf, Obf);
  gemm_bf<0, false><<<dim3(4, 128), 256, 0, stream>>>(
      Obf, w_sa_out, sa_out_b, proj, nullptr, M2, 512, 512, 512);
  ln_kernel<<<M2, 64, 0, stream>>>(src, proj, src, sa_n1_g, sa_n1_b, srcbf);
  gemm_bf_wide<1><<<dim3(4, 128), 256, 0, stream>>>(
      srcbf, w_sa_l1, sa_l1_b, h1bf, M2, 512, 512, 1024);
  gemm_bf<0, false><<<dim3(4, 128), 256, 0, stream>>>(
      h1bf, w_sa_l2, sa_l2_b, proj2, nullptr, M2, 1024, 1024, 512);
  cvt4_kernel<<<dim3(1024, 4), 256, 0, stream>>>(
      ca_q_w, w_ca_q, 262144, ca_k_w, w_ca_k, 262144,
      ca_v_w, w_ca_v, 262144, ca_so_w, w_ca_so, 262144);
  cvt4_kernel<<<dim3(1024, 4), 256, 0, stream>>>(
      ff_l1_w, w_ff_l1, 1048576, ff_l2_w, w_ff_l2, 1048576,
      ff_so_w, w_ff_so, 262144, nullptr, nullptr, 0);
  t2bln_res_kernel<<<M2, 64, 0, stream>>>(
      src, proj2, xnbf, sa_n2_g, sa_n2_b, ca_norm_g, ca_norm_b);

  // ---------- Phase B ----------
  gemm_bf<6, false><<<dim3(4, 128), 256, 0, stream>>>(
      xnbf, w_ca_q, ca_q_b, qch, nullptr, M2, 512, 512, 512);
  t2bln_kernel<<<BB * NN, 64, 0, stream>>>(xf, tnbf, ca_tnorm_g, ca_tnorm_b, NN);
  gemm_bf<0, false><<<dim3(4, 39), 256, 0, stream>>>(
      tnbf, w_ca_k, ca_k_b, kc, nullptr, BB * NN, 512, 512, 512);
  softmax_n_kernel<<<dim3(64, 2), 256, 0, stream>>>(kc);
  gemm_bf<0, false><<<dim3(4, 39), 256, 0, stream>>>(
      tnbf, w_ca_v, ca_v_b, vc, nullptr, BB * NN, 512, 512, 512);
  ctx_kernel<<<BB * HH, 256, 0, stream>>>(kc, vc, ctxTbf);
  gemm_se_kernel<<<dim3(16, 2), 256, 0, stream>>>(
      emb, ca_se_w, ca_se_b, eo, ff_se_w, ff_se_b, eo2);
  lin_y_mfma<<<BB * HH, 256, 0, stream>>>(qch, ctxTbf, yb);
  styl_kernel<<<M2, 64, 0, stream>>>(yb, eo, ca_sn_g, ca_sn_b, hstbf);
  gemm_bf<4, false><<<dim3(4, 128), 256, 0, stream>>>(
      hstbf, w_ca_so, ca_so_b, xbt, xbbf, M2, 512, 512, 512);

  // ---------- Phase C (N-split FFN: full-M dispatches) ----------
  gemm_bf_wide<2><<<dim3(4, 128), 256, 0, stream>>>(
      xbbf, w_ff_l1, ff_l1_b, g1bf, M2, 512, 512, 1024);
  gemm_bf<0, false><<<dim3(4, 128), 256, 0, stream>>>(
      g1bf, w_ff_l2, ff_l2_b, y2, nullptr, M2, 1024, 2048, 512);
  gemm_bf_wide<2><<<dim3(4, 128), 256, 0, stream>>>(
      xbbf, w_ff_l1 + (size_t)1024 * 512, ff_l1_b + 1024, g1bf, M2, 512, 512, 1024);
  gemm_bf<8, false><<<dim3(4, 128), 256, 0, stream>>>(
      g1bf, w_ff_l2 + 1024, ff_l2_b, y2, nullptr, M2, 1024, 2048, 512);
  styl_kernel<<<M2, 64, 0, stream>>>(y2, eo2, ff_sn_g, ff_sn_b, hst2bf);
  gemm_bf<5, false><<<dim3(4, 128), 256, 0, stream>>>(
      hst2bf, w_ff_so, ff_so_b, xbt, dof, M2, 512, 512, 512);
}

// Round 18
// 644.869 us; speedup vs baseline: 1.2041x; 1.2041x over previous
//
#include <hip/hip_runtime.h>
#include <hip/hip_bf16.h>
#include <cstddef>

// Problem dims
#define TT 256
#define BB 64
#define NN 77
#define DD 512
#define SS 334            // T + N + 1
#define HH 8
#define M1 (SS*BB)        // 21376
#define M2 (BB*TT)        // 16384
#define FF 2048

// Workspace: 3 regions of 10,944,512 floats each (125.25 MiB, proven OK).
#define REG 10944512ULL

typedef __attribute__((ext_vector_type(4))) float f32x4;
typedef __attribute__((ext_vector_type(8))) short bf16x8;
typedef __attribute__((ext_vector_type(8))) unsigned short u16x8;

__device__ inline unsigned short f2bf(float f) {
  __hip_bfloat16 h = __float2bfloat16(f);
  return *reinterpret_cast<unsigned short*>(&h);
}
__device__ inline float bf2f(unsigned short u) {
  return __uint_as_float(((unsigned)u) << 16);
}

// ---------------- batched f32 -> bf16 weight converter -----------------
__global__ __launch_bounds__(256) void cvt4_kernel(
    const float* s0, unsigned short* d0, int n0,
    const float* s1, unsigned short* d1, int n1,
    const float* s2, unsigned short* d2, int n2,
    const float* s3, unsigned short* d3, int n3) {
  const float* s; unsigned short* d; int n;
  switch (blockIdx.y) {
    case 0: s = s0; d = d0; n = n0; break;
    case 1: s = s1; d = d1; n = n1; break;
    case 2: s = s2; d = d2; n = n2; break;
    default: s = s3; d = d3; n = n3; break;
  }
  for (int i = (blockIdx.x * 256 + threadIdx.x) * 4; i < n; i += gridDim.x * 1024) {
    float4 v = *(const float4*)(s + i);
    ushort4 u;
    u.x = f2bf(v.x); u.y = f2bf(v.y); u.z = f2bf(v.z); u.w = f2bf(v.w);
    *(ushort4*)(d + i) = u;
  }
}

// ---------------- concat [x; xf; emb] -> src f32 (rows<TT) + bf16 ------
__global__ __launch_bounds__(256) void concat_src_kernel(
    const float* __restrict__ x, const float* __restrict__ xf,
    const float* __restrict__ emb, float* __restrict__ src,
    unsigned short* __restrict__ srcbf) {
  int idx = blockIdx.x * 256 + threadIdx.x;      // float4 index
  if (idx >= SS * BB * 128) return;
  int c4 = idx & 127;
  int row = idx >> 7;                            // s*BB + b
  int s = row >> 6, b = row & 63;
  const float* p;
  if (s < TT)            p = x   + ((size_t)(s * BB + b)) * DD;
  else if (s < TT + NN)  p = xf  + ((size_t)((s - TT) * BB + b)) * DD;
  else                   p = emb + (size_t)b * DD;
  float4 v = ((const float4*)p)[c4];
  if (s < TT)   // f32 src only consumed for rows < TT (ln1 / t2bln_res)
    ((float4*)(src + (size_t)row * DD))[c4] = v;
  ushort4 u;
  u.x = f2bf(v.x); u.y = f2bf(v.y); u.z = f2bf(v.z); u.w = f2bf(v.w);
  ((ushort4*)(srcbf + (size_t)row * DD))[c4] = u;
}

// ---------------- MFMA GEMM (all-bf16, reg-staged, BK=64) --------------
// C = epi(A[M,K]bf16 @ W[N,K]bf16^T + bias); 128x128 tile, 4 waves.
// ldw = W row stride (2048 for ff_l2 column slices).
// EPI: 0 none, 1 relu, 2 gelu, 3 add-into-C(f32),
//      4 add-into-C(f32, T-MAJOR) + write bf16 copy (row-major) to C2,
//      5 out = Cp(f32 T-MAJOR read) + v, write f32 to C2 at (t*BB+b)*512+col,
//      6 fused per-64-col (head) softmax -> bf16 HEAD-MAJOR out,
//      7 scale by 0.125 then bf16 out,
//      8 add-into-C(f32, row-major), NO bias.
template<int EPI, bool CBF>
__global__ __launch_bounds__(256) void gemm_bf(
    const unsigned short* __restrict__ A, const unsigned short* __restrict__ W,
    const float* __restrict__ bias, void* __restrict__ Cp_, void* __restrict__ C2,
    int M, int K, int ldw, int ldc) {
  __shared__ unsigned short As[8][128][8];   // [k-chunk][row][k8]
  __shared__ unsigned short Bs[8][128][8];
  const int tid = threadIdx.x;
  // XCD swizzle
  int bxt, byt;
  {
    int total = gridDim.x * gridDim.y;
    int raw = blockIdx.y * gridDim.x + blockIdx.x;
    if ((total & 7) == 0) {
      int lid = (raw & 7) * (total >> 3) + (raw >> 3);
      bxt = lid % gridDim.x;
      byt = lid / gridDim.x;
    } else { bxt = blockIdx.x; byt = blockIdx.y; }
  }
  const int bm = byt * 128;
  const int bn = bxt * 128;
  const int lane = tid & 63;
  const int wave = tid >> 6;
  const int wr = wave >> 1, wc = wave & 1;
  const int q = lane >> 4, lr = lane & 15;

  f32x4 acc[4][4];
#pragma unroll
  for (int m = 0; m < 4; ++m)
#pragma unroll
    for (int n = 0; n < 4; ++n) acc[m][n] = (f32x4){0.f, 0.f, 0.f, 0.f};

  const int srow = tid >> 1;
  const int sk = (tid & 1) * 32;
  const int c0 = (tid & 1) * 4;
  int arow = bm + srow; if (arow >= M) arow = M - 1;
  const unsigned short* Ag = A + (size_t)arow * K + sk;
  const unsigned short* Wg = W + (size_t)(bn + srow) * ldw + sk;

  for (int k0 = 0; k0 < K; k0 += 64) {
    u16x8 a0 = *(const u16x8*)(Ag + k0);
    u16x8 a1 = *(const u16x8*)(Ag + k0 + 8);
    u16x8 a2 = *(const u16x8*)(Ag + k0 + 16);
    u16x8 a3 = *(const u16x8*)(Ag + k0 + 24);
    u16x8 b0 = *(const u16x8*)(Wg + k0);
    u16x8 b1 = *(const u16x8*)(Wg + k0 + 8);
    u16x8 b2 = *(const u16x8*)(Wg + k0 + 16);
    u16x8 b3 = *(const u16x8*)(Wg + k0 + 24);
    __syncthreads();
    *(u16x8*)&As[c0 + 0][srow][0] = a0;
    *(u16x8*)&As[c0 + 1][srow][0] = a1;
    *(u16x8*)&As[c0 + 2][srow][0] = a2;
    *(u16x8*)&As[c0 + 3][srow][0] = a3;
    *(u16x8*)&Bs[c0 + 0][srow][0] = b0;
    *(u16x8*)&Bs[c0 + 1][srow][0] = b1;
    *(u16x8*)&Bs[c0 + 2][srow][0] = b2;
    *(u16x8*)&Bs[c0 + 3][srow][0] = b3;
    __syncthreads();
#pragma unroll
    for (int ks = 0; ks < 2; ++ks) {
      bf16x8 af[4], bf[4];
#pragma unroll
      for (int m = 0; m < 4; ++m)
        af[m] = *(const bf16x8*)&As[ks * 4 + q][wr * 64 + m * 16 + lr][0];
#pragma unroll
      for (int n = 0; n < 4; ++n)
        bf[n] = *(const bf16x8*)&Bs[ks * 4 + q][wc * 64 + n * 16 + lr][0];
#pragma unroll
      for (int m = 0; m < 4; ++m)
#pragma unroll
        for (int n = 0; n < 4; ++n)
          acc[m][n] = __builtin_amdgcn_mfma_f32_16x16x32_bf16(af[m], bf[n], acc[m][n], 0, 0, 0);
    }
  }

  if (EPI == 6) {
    const int hcol = (bn >> 6) + wc;     // head of this wave's 64-col span
#pragma unroll
    for (int m = 0; m < 4; ++m) {
#pragma unroll
      for (int i = 0; i < 4; ++i) {
        float vv[4];
        float mx = -1e30f;
#pragma unroll
        for (int n = 0; n < 4; ++n) {
          float v = acc[m][n][i] + bias[bn + wc * 64 + n * 16 + lr];
          vv[n] = v; mx = fmaxf(mx, v);
        }
#pragma unroll
        for (int off = 8; off; off >>= 1) mx = fmaxf(mx, __shfl_xor(mx, off));
        float sum = 0.f;
#pragma unroll
        for (int n = 0; n < 4; ++n) { vv[n] = __expf(vv[n] - mx); sum += vv[n]; }
#pragma unroll
        for (int off = 8; off; off >>= 1) sum += __shfl_xor(sum, off);
        float inv = 1.f / sum;
        const int row = bm + wr * 64 + m * 16 + q * 4 + i;
        const int t = row & 255, b2 = row >> 8;
        unsigned short* dst =
            (unsigned short*)Cp_ + (((size_t)(b2 * 8 + hcol) * 256 + t) << 6);
#pragma unroll
        for (int n = 0; n < 4; ++n)
          dst[n * 16 + lr] = f2bf(vv[n] * inv);
      }
    }
    return;
  }

#pragma unroll
  for (int m = 0; m < 4; ++m) {
#pragma unroll
    for (int n = 0; n < 4; ++n) {
      const int col = bn + wc * 64 + n * 16 + lr;
      const float bb = (EPI == 8) ? 0.f : bias[col];
#pragma unroll
      for (int i = 0; i < 4; ++i) {
        const int row = bm + wr * 64 + m * 16 + q * 4 + i;
        if (row < M) {
          float v = acc[m][n][i] + bb;
          if (EPI == 1) v = fmaxf(v, 0.f);
          if (EPI == 2) v = 0.5f * v * (1.f + erff(v * 0.70710678118f));
          if (EPI == 7) v *= 0.125f;
          if (EPI <= 2 || EPI == 7) {
            if (CBF) ((unsigned short*)Cp_)[(size_t)row * ldc + col] = f2bf(v);
            else     ((float*)Cp_)[(size_t)row * ldc + col] = v;
          } else if (EPI == 3 || EPI == 8) {
            ((float*)Cp_)[(size_t)row * ldc + col] += v;
          } else if (EPI == 4) {
            const int t = row & 255, b2 = row >> 8;
            float* C = (float*)Cp_ + ((size_t)(t * BB + b2)) * DD + col;
            float o = *C + v; *C = o;
            ((unsigned short*)C2)[(size_t)row * ldc + col] = f2bf(o);
          } else {  // EPI == 5
            const int t = row & 255, b2 = row >> 8;
            const size_t idx = ((size_t)(t * BB + b2)) * DD + col;
            float o = ((const float*)Cp_)[idx] + v;
            ((float*)C2)[idx] = o;
          }
        }
      }
    }
  }
}

// ---------------- MFMA flash attention: 128 queries per block ----------
__global__ __launch_bounds__(256) void attn_mfma_kernel(
    const unsigned short* __restrict__ Qb, const unsigned short* __restrict__ KVb,
    unsigned short* __restrict__ Ob) {
  __shared__ unsigned short Qs[128][72];
  __shared__ unsigned short Ks[64][72];
  __shared__ unsigned short Vt[64][72];
  __shared__ unsigned short Ps[4][16][72];
  const int bh = blockIdx.y, b = bh >> 3, h = bh & 7;
  const int s0 = blockIdx.x << 7;
  const int tid = threadIdx.x;
  const int wave = tid >> 6, lane = tid & 63;
  const int q = lane >> 4, lr = lane & 15;
  const int sr = tid >> 2;
  const int c0 = (tid & 3) << 4;
#pragma unroll
  for (int it = 0; it < 4; ++it) {
    int v = it * 256 + tid;
    int row = v >> 3, col = (v & 7) * 8;
    u16x8 d8 = *(const u16x8*)(Qb + ((size_t)((s0 + row) * BB + b)) * 512 + h * 64 + col);
    *(u16x8*)&Qs[row][col] = d8;
  }
  f32x4 oacc[2][4];
#pragma unroll
  for (int m = 0; m < 2; ++m)
#pragma unroll
    for (int dt = 0; dt < 4; ++dt) oacc[m][dt] = (f32x4){0.f, 0.f, 0.f, 0.f};
  float m_r[2][4], l_r[2][4];
#pragma unroll
  for (int m = 0; m < 2; ++m)
#pragma unroll
    for (int i = 0; i < 4; ++i) { m_r[m][i] = -1e30f; l_r[m][i] = 0.f; }

  for (int kt = 0; kt < 6; ++kt) {
    __syncthreads();
    {
      int t = kt * 64 + sr;
      u16x8 k0 = {0, 0, 0, 0, 0, 0, 0, 0}, k1 = k0, w0 = k0, w1 = k0;
      if (t < SS) {
        const unsigned short* kp = KVb + ((size_t)(t * BB + b)) * 1024 + h * 64 + c0;
        k0 = *(const u16x8*)kp; k1 = *(const u16x8*)(kp + 8);
        w0 = *(const u16x8*)(kp + 512); w1 = *(const u16x8*)(kp + 520);
      }
      *(u16x8*)&Ks[sr][c0] = k0;
      *(u16x8*)&Ks[sr][c0 + 8] = k1;
#pragma unroll
      for (int j = 0; j < 8; ++j) Vt[c0 + j][sr] = w0[j];
#pragma unroll
      for (int j = 0; j < 8; ++j) Vt[c0 + 8 + j][sr] = w1[j];
    }
    __syncthreads();
#pragma unroll
    for (int m = 0; m < 2; ++m) {
      f32x4 sacc[4];
#pragma unroll
      for (int ct = 0; ct < 4; ++ct) sacc[ct] = (f32x4){0.f, 0.f, 0.f, 0.f};
#pragma unroll
      for (int kc = 0; kc < 2; ++kc) {
        bf16x8 aq = *(const bf16x8*)&Qs[wave * 32 + m * 16 + lr][kc * 32 + q * 8];
#pragma unroll
        for (int ct = 0; ct < 4; ++ct) {
          bf16x8 bk = *(const bf16x8*)&Ks[ct * 16 + lr][kc * 32 + q * 8];
          sacc[ct] = __builtin_amdgcn_mfma_f32_16x16x32_bf16(aq, bk, sacc[ct], 0, 0, 0);
        }
      }
      if (kt == 5) {
#pragma unroll
        for (int ct = 0; ct < 4; ++ct)
          if (320 + ct * 16 + lr >= SS) {
#pragma unroll
            for (int i = 0; i < 4; ++i) sacc[ct][i] = -1e30f;
          }
      }
      float pexp[4][4];
#pragma unroll
      for (int i = 0; i < 4; ++i) {
        float mt = fmaxf(fmaxf(sacc[0][i], sacc[1][i]), fmaxf(sacc[2][i], sacc[3][i]));
#pragma unroll
        for (int off = 8; off; off >>= 1) mt = fmaxf(mt, __shfl_xor(mt, off));
        float mn = fmaxf(m_r[m][i], mt);
        float rescale = __expf(m_r[m][i] - mn);
        m_r[m][i] = mn;
        float se = 0.f;
#pragma unroll
        for (int ct = 0; ct < 4; ++ct) {
          float e = __expf(sacc[ct][i] - mn);
          pexp[ct][i] = e;
          se += e;
        }
#pragma unroll
        for (int off = 8; off; off >>= 1) se += __shfl_xor(se, off);
        l_r[m][i] = l_r[m][i] * rescale + se;
#pragma unroll
        for (int dt = 0; dt < 4; ++dt) oacc[m][dt][i] *= rescale;
      }
#pragma unroll
      for (int ct = 0; ct < 4; ++ct)
#pragma unroll
        for (int i = 0; i < 4; ++i)
          Ps[wave][q * 4 + i][ct * 16 + lr] = f2bf(pexp[ct][i]);
#pragma unroll
      for (int kc = 0; kc < 2; ++kc) {
        bf16x8 ap = *(const bf16x8*)&Ps[wave][lr][kc * 32 + q * 8];
#pragma unroll
        for (int dt = 0; dt < 4; ++dt) {
          bf16x8 bv = *(const bf16x8*)&Vt[dt * 16 + lr][kc * 32 + q * 8];
          oacc[m][dt] = __builtin_amdgcn_mfma_f32_16x16x32_bf16(ap, bv, oacc[m][dt], 0, 0, 0);
        }
      }
    }
  }
#pragma unroll
  for (int m = 0; m < 2; ++m) {
#pragma unroll
    for (int i = 0; i < 4; ++i) {
      int s = s0 + wave * 32 + m * 16 + q * 4 + i;
      float inv = 1.f / l_r[m][i];
      unsigned short* op = Ob + ((size_t)(s * BB + b)) * 512 + h * 64;
#pragma unroll
      for (int dt = 0; dt < 4; ++dt)
        op[dt * 16 + lr] = f2bf(oacc[m][dt][i] * inv);
    }
  }
}

// ------- MFMA linear-attn PV -------------------------------------------
__global__ __launch_bounds__(256) void lin_y_mfma(
    const unsigned short* __restrict__ qch, const unsigned short* __restrict__ ctxT,
    float* __restrict__ y) {
  __shared__ unsigned short Qs[256][72];
  __shared__ unsigned short Cs[64][72];
  const int bh = blockIdx.x, b = bh >> 3, h = bh & 7;
  const int tid = threadIdx.x;
  const int wave = tid >> 6, lane = tid & 63;
  const int q = lane >> 4, lr = lane & 15;
  {
    const unsigned short* qp = qch + (size_t)bh * 16384;
#pragma unroll
    for (int it = 0; it < 8; ++it) {
      int v = it * 256 + tid;
      u16x8 d8 = *(const u16x8*)(qp + v * 8);
      *(u16x8*)&Qs[v >> 3][(v & 7) * 8] = d8;
    }
    const unsigned short* cp = ctxT + (size_t)bh * 4096;
#pragma unroll
    for (int it = 0; it < 2; ++it) {
      int v = it * 256 + tid;
      u16x8 d8 = *(const u16x8*)(cp + v * 8);
      *(u16x8*)&Cs[v >> 3][(v & 7) * 8] = d8;
    }
  }
  __syncthreads();
  f32x4 acc[4][4];
#pragma unroll
  for (int m = 0; m < 4; ++m)
#pragma unroll
    for (int n = 0; n < 4; ++n) acc[m][n] = (f32x4){0.f, 0.f, 0.f, 0.f};
#pragma unroll
  for (int kc = 0; kc < 2; ++kc) {
    bf16x8 af[4], bf[4];
#pragma unroll
    for (int m = 0; m < 4; ++m)
      af[m] = *(const bf16x8*)&Qs[wave * 64 + m * 16 + lr][kc * 32 + q * 8];
#pragma unroll
    for (int n = 0; n < 4; ++n)
      bf[n] = *(const bf16x8*)&Cs[n * 16 + lr][kc * 32 + q * 8];
#pragma unroll
    for (int m = 0; m < 4; ++m)
#pragma unroll
      for (int n = 0; n < 4; ++n)
        acc[m][n] = __builtin_amdgcn_mfma_f32_16x16x32_bf16(af[m], bf[n], acc[m][n], 0, 0, 0);
  }
#pragma unroll
  for (int m = 0; m < 4; ++m) {
#pragma unroll
    for (int n = 0; n < 4; ++n) {
#pragma unroll
      for (int i = 0; i < 4; ++i) {
        int t = wave * 64 + m * 16 + q * 4 + i;
        y[((size_t)(b * TT + t)) * DD + h * 64 + n * 16 + lr] = acc[m][n][i];
      }
    }
  }
}

// ------- fused silu + both stylization emb linears (eo, eo2) -----------
__global__ __launch_bounds__(256) void gemm_se_kernel(
    const float* __restrict__ emb,
    const float* __restrict__ w0, const float* __restrict__ b0, float* __restrict__ c0_,
    const float* __restrict__ w1, const float* __restrict__ b1, float* __restrict__ c1_) {
  __shared__ float As[16][64];
  __shared__ float Ws[16][64];
  const float* W    = blockIdx.y ? w1 : w0;
  const float* bias = blockIdx.y ? b1 : b0;
  float* C          = blockIdx.y ? c1_ : c0_;
  const int tid = threadIdx.x;
  const int bn = blockIdx.x << 6;
  const int lr = tid >> 2;
  const int lk = (tid & 3) << 2;
  const float* Ap = emb + (size_t)lr * 512 + lk;
  const float* Wp = W + (size_t)(bn + lr) * 512 + lk;
  const int tx = tid & 15, ty = tid >> 4;
  float c[4][4] = {};
  for (int k0 = 0; k0 < 512; k0 += 16) {
    float4 av = *(const float4*)(Ap + k0);
    av.x = av.x / (1.f + __expf(-av.x));
    av.y = av.y / (1.f + __expf(-av.y));
    av.z = av.z / (1.f + __expf(-av.z));
    av.w = av.w / (1.f + __expf(-av.w));
    float4 wv = *(const float4*)(Wp + k0);
    __syncthreads();
    As[lk + 0][lr] = av.x; As[lk + 1][lr] = av.y;
    As[lk + 2][lr] = av.z; As[lk + 3][lr] = av.w;
    Ws[lk + 0][lr] = wv.x; Ws[lk + 1][lr] = wv.y;
    Ws[lk + 2][lr] = wv.z; Ws[lk + 3][lr] = wv.w;
    __syncthreads();
#pragma unroll
    for (int k = 0; k < 16; ++k) {
      const float4 a = *(const float4*)&As[k][ty << 2];
      const float4 w = *(const float4*)&Ws[k][tx << 2];
      c[0][0] += a.x * w.x; c[0][1] += a.x * w.y; c[0][2] += a.x * w.z; c[0][3] += a.x * w.w;
      c[1][0] += a.y * w.x; c[1][1] += a.y * w.y; c[1][2] += a.y * w.z; c[1][3] += a.y * w.w;
      c[2][0] += a.z * w.x; c[2][1] += a.z * w.y; c[2][2] += a.z * w.z; c[2][3] += a.z * w.w;
      c[3][0] += a.w * w.x; c[3][1] += a.w * w.y; c[3][2] += a.w * w.z; c[3][3] += a.w * w.w;
    }
  }
#pragma unroll
  for (int i = 0; i < 4; ++i) {
    int row = (ty << 2) + i;
    float* Cp = C + (size_t)row * 1024 + bn + (tx << 2);
#pragma unroll
    for (int j = 0; j < 4; ++j)
      Cp[j] = c[i][j] + bias[bn + (tx << 2) + j];
  }
}

// ---------------- LayerNorm row kernel: f32 out + optional bf16 out ----
__global__ __launch_bounds__(64) void ln_kernel(
    const float* __restrict__ in, const float* __restrict__ res,
    float* __restrict__ out, const float* __restrict__ g,
    const float* __restrict__ beta, unsigned short* __restrict__ obf) {
  const int row = blockIdx.x;
  const int lane = threadIdx.x;
  const float* ip = in + (size_t)row * DD;
  float v[8];
  float s = 0.f, ss = 0.f;
#pragma unroll
  for (int u = 0; u < 2; ++u) {
    int d = u * 256 + lane * 4;
    float4 a = *(const float4*)(ip + d);
    if (res) {
      float4 r = *(const float4*)(res + (size_t)row * DD + d);
      a.x += r.x; a.y += r.y; a.z += r.z; a.w += r.w;
    }
    v[u * 4 + 0] = a.x; v[u * 4 + 1] = a.y; v[u * 4 + 2] = a.z; v[u * 4 + 3] = a.w;
    s += a.x + a.y + a.z + a.w;
    ss += a.x * a.x + a.y * a.y + a.z * a.z + a.w * a.w;
  }
#pragma unroll
  for (int off = 32; off; off >>= 1) { s += __shfl_xor(s, off); ss += __shfl_xor(ss, off); }
  float mean = s * (1.f / 512.f);
  float var = ss * (1.f / 512.f) - mean * mean;
  float rstd = rsqrtf(var + 1e-5f);
  float* op = out + (size_t)row * DD;
#pragma unroll
  for (int u = 0; u < 2; ++u) {
    int d = u * 256 + lane * 4;
    float4 o4;
    o4.x = (v[u * 4 + 0] - mean) * rstd * g[d + 0] + beta[d + 0];
    o4.y = (v[u * 4 + 1] - mean) * rstd * g[d + 1] + beta[d + 1];
    o4.z = (v[u * 4 + 2] - mean) * rstd * g[d + 2] + beta[d + 2];
    o4.w = (v[u * 4 + 3] - mean) * rstd * g[d + 3] + beta[d + 3];
    *(float4*)(op + d) = o4;
    if (obf) {
      ushort4 u4;
      u4.x = f2bf(o4.x); u4.y = f2bf(o4.y); u4.z = f2bf(o4.z); u4.w = f2bf(o4.w);
      *(ushort4*)(obf + (size_t)row * DD + d) = u4;
    }
  }
}

// ------- fused residual-LN (IN-PLACE, t-major) + second LN (bf16 out) --
__global__ __launch_bounds__(64) void t2bln_res_kernel(
    float* __restrict__ src, const float* __restrict__ proj2,
    unsigned short* __restrict__ xnbf,
    const float* __restrict__ g2, const float* __restrict__ b2,
    const float* __restrict__ gca, const float* __restrict__ bca) {
  const int row = blockIdx.x;          // t*BB + b
  const int t = row >> 6, b = row & 63;
  const size_t soff = (size_t)row * DD;
  const int lane = threadIdx.x;
  float v[8];
  float s = 0.f, ss = 0.f;
#pragma unroll
  for (int u = 0; u < 2; ++u) {
    int d = u * 256 + lane * 4;
    float4 a = *(const float4*)(src + soff + d);
    float4 r = *(const float4*)(proj2 + soff + d);
    a.x += r.x; a.y += r.y; a.z += r.z; a.w += r.w;
    v[u * 4 + 0] = a.x; v[u * 4 + 1] = a.y; v[u * 4 + 2] = a.z; v[u * 4 + 3] = a.w;
    s += a.x + a.y + a.z + a.w;
    ss += a.x * a.x + a.y * a.y + a.z * a.z + a.w * a.w;
  }
#pragma unroll
  for (int off = 32; off; off >>= 1) { s += __shfl_xor(s, off); ss += __shfl_xor(ss, off); }
  float mean = s * (1.f / 512.f);
  float var = ss * (1.f / 512.f) - mean * mean;
  float rstd = rsqrtf(var + 1e-5f);
  float s2 = 0.f, ss2 = 0.f;
#pragma unroll
  for (int u = 0; u < 8; ++u) {
    int d = (u >> 2) * 256 + lane * 4 + (u & 3);
    float o = (v[u] - mean) * rstd * g2[d] + b2[d];
    v[u] = o;
    s2 += o; ss2 += o * o;
  }
#pragma unroll
  for (int u = 0; u < 2; ++u) {
    int d = u * 256 + lane * 4;
    float4 o4 = {v[u * 4 + 0], v[u * 4 + 1], v[u * 4 + 2], v[u * 4 + 3]};
    *(float4*)(src + soff + d) = o4;
  }
#pragma unroll
  for (int off = 32; off; off >>= 1) { s2 += __shfl_xor(s2, off); ss2 += __shfl_xor(ss2, off); }
  float mean2 = s2 * (1.f / 512.f);
  float var2 = ss2 * (1.f / 512.f) - mean2 * mean2;
  float rstd2 = rsqrtf(var2 + 1e-5f);
  const size_t orow = (size_t)(b * TT + t) * DD;
#pragma unroll
  for (int u = 0; u < 2; ++u) {
    int d = u * 256 + lane * 4;
    ushort4 u4;
    u4.x = f2bf((v[u * 4 + 0] - mean2) * rstd2 * gca[d + 0] + bca[d + 0]);
    u4.y = f2bf((v[u * 4 + 1] - mean2) * rstd2 * gca[d + 1] + bca[d + 1]);
    u4.z = f2bf((v[u * 4 + 2] - mean2) * rstd2 * gca[d + 2] + bca[d + 2]);
    u4.w = f2bf((v[u * 4 + 3] - mean2) * rstd2 * gca[d + 3] + bca[d + 3]);
    *(ushort4*)(xnbf + orow + d) = u4;
  }
}

// ------- fused transpose + LN (xf path) --------------------------------
__global__ __launch_bounds__(64) void t2bln_kernel(
    const float* __restrict__ in, unsigned short* __restrict__ obf,
    const float* __restrict__ g, const float* __restrict__ beta, int Rr) {
  const int rp = blockIdx.x;
  const int b = rp / Rr, r = rp % Rr;
  const float* ip = in + ((size_t)(r * BB + b)) * DD;
  const int lane = threadIdx.x;
  float v[8];
  float s = 0.f, ss = 0.f;
#pragma unroll
  for (int u = 0; u < 2; ++u) {
    int d = u * 256 + lane * 4;
    float4 a = *(const float4*)(ip + d);
    v[u * 4 + 0] = a.x; v[u * 4 + 1] = a.y; v[u * 4 + 2] = a.z; v[u * 4 + 3] = a.w;
    s += a.x + a.y + a.z + a.w;
    ss += a.x * a.x + a.y * a.y + a.z * a.z + a.w * a.w;
  }
#pragma unroll
  for (int off = 32; off; off >>= 1) { s += __shfl_xor(s, off); ss += __shfl_xor(ss, off); }
  float mean = s * (1.f / 512.f);
  float var = ss * (1.f / 512.f) - mean * mean;
  float rstd = rsqrtf(var + 1e-5f);
#pragma unroll
  for (int u = 0; u < 2; ++u) {
    int d = u * 256 + lane * 4;
    ushort4 u4;
    u4.x = f2bf((v[u * 4 + 0] - mean) * rstd * g[d + 0] + beta[d + 0]);
    u4.y = f2bf((v[u * 4 + 1] - mean) * rstd * g[d + 1] + beta[d + 1]);
    u4.z = f2bf((v[u * 4 + 2] - mean) * rstd * g[d + 2] + beta[d + 2]);
    u4.w = f2bf((v[u * 4 + 3] - mean) * rstd * g[d + 3] + beta[d + 3]);
    *(ushort4*)(obf + (size_t)rp * DD + d) = u4;
  }
}

// ---------------- stylization: silu(LN(y)*(1+scale)+shift) -> bf16 -----
__global__ __launch_bounds__(64) void styl_kernel(
    const float* __restrict__ y, const float* __restrict__ eo,
    const float* __restrict__ g, const float* __restrict__ beta,
    unsigned short* __restrict__ out) {
  const int row = blockIdx.x;         // b*TT + t
  const int b = row >> 8;
  const int lane = threadIdx.x;
  const float* ip = y + (size_t)row * DD;
  const float* sc = eo + (size_t)b * 1024;
  float v[8];
  float s = 0.f, ss = 0.f;
#pragma unroll
  for (int u = 0; u < 2; ++u) {
    int d = u * 256 + lane * 4;
    float4 a = *(const float4*)(ip + d);
    v[u * 4 + 0] = a.x; v[u * 4 + 1] = a.y; v[u * 4 + 2] = a.z; v[u * 4 + 3] = a.w;
    s += a.x + a.y + a.z + a.w;
    ss += a.x * a.x + a.y * a.y + a.z * a.z + a.w * a.w;
  }
#pragma unroll
  for (int off = 32; off; off >>= 1) { s += __shfl_xor(s, off); ss += __shfl_xor(ss, off); }
  float mean = s * (1.f / 512.f);
  float var = ss * (1.f / 512.f) - mean * mean;
  float rstd = rsqrtf(var + 1e-5f);
#pragma unroll
  for (int u = 0; u < 2; ++u) {
    int d0 = u * 256 + lane * 4;
    ushort4 u4;
#pragma unroll
    for (int j = 0; j < 4; ++j) {
      int d = d0 + j;
      float ln = (v[u * 4 + j] - mean) * rstd * g[d] + beta[d];
      float h = ln * (1.f + sc[d]) + sc[512 + d];
      float r = h / (1.f + __expf(-h));
      ((unsigned short*)&u4)[j] = f2bf(r);
    }
    *(ushort4*)(out + (size_t)row * DD + d0) = u4;
  }
}

// ---------------- softmax over n (kc, axis=1, 77 tokens) ---------------
__global__ __launch_bounds__(256) void softmax_n_kernel(float* __restrict__ a) {
  int b = blockIdx.x;
  int c = blockIdx.y * 256 + threadIdx.x;
  float* p = a + ((size_t)b * NN) * DD + c;
  float m = -1e30f;
  for (int n = 0; n < NN; ++n) m = fmaxf(m, p[(size_t)n * DD]);
  float sum = 0.f;
  for (int n = 0; n < NN; ++n) sum += __expf(p[(size_t)n * DD] - m);
  float inv = 1.f / sum;
  for (int n = 0; n < NN; ++n) p[(size_t)n * DD] = __expf(p[(size_t)n * DD] - m) * inv;
}

// ------- ctx: ctxT[bh][l][d] (bf16) = sum_n kc[b,n,h,d]*vc[b,n,h,l] ----
__global__ __launch_bounds__(256) void ctx_kernel(
    const float* __restrict__ kc, const float* __restrict__ vc,
    unsigned short* __restrict__ ctxT) {
  __shared__ float ks[NN][64];
  __shared__ float vs[NN][64];
  int bh = blockIdx.x; int b = bh >> 3, h = bh & 7;
  for (int l = threadIdx.x; l < NN * 64; l += 256) {
    int n = l >> 6, d = l & 63;
    size_t idx = ((size_t)(b * NN + n)) * DD + h * 64 + d;
    ks[n][d] = kc[idx];
    vs[n][d] = vc[idx];
  }
  __syncthreads();
  int d = threadIdx.x >> 2;
  int l0 = (threadIdx.x & 3) << 4;
  float acc[16] = {};
  for (int n = 0; n < NN; ++n) {
    float kd = ks[n][d];
#pragma unroll
    for (int j = 0; j < 16; ++j) acc[j] += kd * vs[n][l0 + j];
  }
  unsigned short* cp = ctxT + (size_t)bh * 4096 + d;
#pragma unroll
  for (int j = 0; j < 16; ++j) cp[(size_t)(l0 + j) * 64] = f2bf(acc[j]);
}

extern "C" void kernel_launch(void* const* d_in, const int* in_sizes, int n_in,
                              void* d_out, int out_size, void* d_ws, size_t ws_size,
                              hipStream_t stream) {
  const float* x       = (const float*)d_in[0];
  const float* xf      = (const float*)d_in[1];
  const float* emb     = (const float*)d_in[2];
  const float* sa_in_w = (const float*)d_in[3];
  const float* sa_in_b = (const float*)d_in[4];
  const float* sa_out_w= (const float*)d_in[5];
  const float* sa_out_b= (const float*)d_in[6];
  const float* sa_l1_w = (const float*)d_in[7];
  const float* sa_l1_b = (const float*)d_in[8];
  const float* sa_l2_w = (const float*)d_in[9];
  const float* sa_l2_b = (const float*)d_in[10];
  const float* sa_n1_g = (const float*)d_in[11];
  const float* sa_n1_b = (const float*)d_in[12];
  const float* sa_n2_g = (const float*)d_in[13];
  const float* sa_n2_b = (const float*)d_in[14];
  const float* ca_norm_g = (const float*)d_in[15];
  const float* ca_norm_b = (const float*)d_in[16];
  const float* ca_tnorm_g= (const float*)d_in[17];
  const float* ca_tnorm_b= (const float*)d_in[18];
  const float* ca_q_w  = (const float*)d_in[19];
  const float* ca_q_b  = (const float*)d_in[20];
  const float* ca_k_w  = (const float*)d_in[21];
  const float* ca_k_b  = (const float*)d_in[22];
  const float* ca_v_w  = (const float*)d_in[23];
  const float* ca_v_b  = (const float*)d_in[24];
  const float* ca_se_w = (const float*)d_in[25];
  const float* ca_se_b = (const float*)d_in[26];
  const float* ca_sn_g = (const float*)d_in[27];
  const float* ca_sn_b = (const float*)d_in[28];
  const float* ca_so_w = (const float*)d_in[29];
  const float* ca_so_b = (const float*)d_in[30];
  const float* ff_l1_w = (const float*)d_in[31];
  const float* ff_l1_b = (const float*)d_in[32];
  const float* ff_l2_w = (const float*)d_in[33];
  const float* ff_l2_b = (const float*)d_in[34];
  const float* ff_se_w = (const float*)d_in[35];
  const float* ff_se_b = (const float*)d_in[36];
  const float* ff_sn_g = (const float*)d_in[37];
  const float* ff_sn_b = (const float*)d_in[38];
  const float* ff_so_w = (const float*)d_in[39];
  const float* ff_so_b = (const float*)d_in[40];

  float* R1 = (float*)d_ws;
  float* R2 = R1 + REG;
  float* R3 = R2 + REG;
  float* dof = (float*)d_out;

  // bf16 weight slots
  unsigned short* w_sa_in  = (unsigned short*)dof;
  unsigned short* w_sa_out = w_sa_in + 786432;
  unsigned short* w_sa_l1  = w_sa_out + 262144;
  unsigned short* w_sa_l2  = w_sa_l1 + 524288;
  unsigned short* srcbf    = (unsigned short*)(dof + 1048576);
  unsigned short* w_ca_q  = (unsigned short*)(R2 + 8552448);
  unsigned short* w_ca_k  = w_ca_q + 262144;
  unsigned short* w_ca_v  = w_ca_k + 262144;
  unsigned short* w_ca_so = w_ca_v + 262144;
  unsigned short* w_ff_l1 = (unsigned short*)(R2 + 9076736);
  unsigned short* w_ff_l2 = w_ff_l1 + 1048576;
  unsigned short* w_ff_so = w_ff_l2 + 1048576;

  // Phase A aliases
  float* src = R1;
  unsigned short* Qbf  = (unsigned short*)R3;
  unsigned short* Obf  = (unsigned short*)(R3 + 5472256);
  unsigned short* KVbf = (unsigned short*)R2;
  float* proj  = R2;
  unsigned short* h1bf = (unsigned short*)R2;
  float* proj2 = R3;
  float* xbt = R1;
  // Phase B aliases
  unsigned short* xnbf = (unsigned short*)R2;
  unsigned short* tnbf = (unsigned short*)(R2 + 4194304);
  unsigned short* qch = (unsigned short*)dof;
  float* kc  = R3;
  float* vc  = R3 + 2523136;
  unsigned short* ctxTbf = (unsigned short*)(R3 + 5046272);
  unsigned short* hstbf = (unsigned short*)(R3 + 6094848);
  unsigned short* xbbf  = (unsigned short*)(R3 + 8192000);
  float* eo  = R2 + 8421376;
  float* eo2 = eo + 65536;
  float* yb  = R2;
  // Phase C aliases
  unsigned short* g1bf = (unsigned short*)R2;
  float* y2 = dof;
  unsigned short* hst2bf = (unsigned short*)R3;

  // ---------- Phase A ----------
  cvt4_kernel<<<dim3(1024, 4), 256, 0, stream>>>(
      sa_in_w, w_sa_in, 786432, sa_out_w, w_sa_out, 262144,
      sa_l1_w, w_sa_l1, 524288, sa_l2_w, w_sa_l2, 524288);
  concat_src_kernel<<<10688, 256, 0, stream>>>(x, xf, emb, src, srcbf);
  gemm_bf<7, true><<<dim3(4, 128), 256, 0, stream>>>(
      srcbf, w_sa_in, sa_in_b, Qbf, nullptr, M2, 512, 512, 512);
  gemm_bf<0, true><<<dim3(8, 167), 256, 0, stream>>>(
      srcbf, w_sa_in + (size_t)512 * 512, sa_in_b + 512, KVbf, nullptr, M1, 512, 512, 1024);
  attn_mfma_kernel<<<dim3(2, BB * HH), 256, 0, stream>>>(Qbf, KVbf, Obf);
  gemm_bf<0, false><<<dim3(4, 128), 256, 0, stream>>>(
      Obf, w_sa_out, sa_out_b, proj, nullptr, M2, 512, 512, 512);
  ln_kernel<<<M2, 64, 0, stream>>>(src, proj, src, sa_n1_g, sa_n1_b, srcbf);
  gemm_bf<1, true><<<dim3(8, 128), 256, 0, stream>>>(
      srcbf, w_sa_l1, sa_l1_b, h1bf, nullptr, M2, 512, 512, 1024);
  gemm_bf<0, false><<<dim3(4, 128), 256, 0, stream>>>(
      h1bf, w_sa_l2, sa_l2_b, proj2, nullptr, M2, 1024, 1024, 512);
  cvt4_kernel<<<dim3(1024, 4), 256, 0, stream>>>(
      ca_q_w, w_ca_q, 262144, ca_k_w, w_ca_k, 262144,
      ca_v_w, w_ca_v, 262144, ca_so_w, w_ca_so, 262144);
  cvt4_kernel<<<dim3(1024, 4), 256, 0, stream>>>(
      ff_l1_w, w_ff_l1, 1048576, ff_l2_w, w_ff_l2, 1048576,
      ff_so_w, w_ff_so, 262144, nullptr, nullptr, 0);
  t2bln_res_kernel<<<M2, 64, 0, stream>>>(
      src, proj2, xnbf, sa_n2_g, sa_n2_b, ca_norm_g, ca_norm_b);

  // ---------- Phase B ----------
  gemm_bf<6, false><<<dim3(4, 128), 256, 0, stream>>>(
      xnbf, w_ca_q, ca_q_b, qch, nullptr, M2, 512, 512, 512);
  t2bln_kernel<<<BB * NN, 64, 0, stream>>>(xf, tnbf, ca_tnorm_g, ca_tnorm_b, NN);
  gemm_bf<0, false><<<dim3(4, 39), 256, 0, stream>>>(
      tnbf, w_ca_k, ca_k_b, kc, nullptr, BB * NN, 512, 512, 512);
  softmax_n_kernel<<<dim3(64, 2), 256, 0, stream>>>(kc);
  gemm_bf<0, false><<<dim3(4, 39), 256, 0, stream>>>(
      tnbf, w_ca_v, ca_v_b, vc, nullptr, BB * NN, 512, 512, 512);
  ctx_kernel<<<BB * HH, 256, 0, stream>>>(kc, vc, ctxTbf);
  gemm_se_kernel<<<dim3(16, 2), 256, 0, stream>>>(
      emb, ca_se_w, ca_se_b, eo, ff_se_w, ff_se_b, eo2);
  lin_y_mfma<<<BB * HH, 256, 0, stream>>>(qch, ctxTbf, yb);
  styl_kernel<<<M2, 64, 0, stream>>>(yb, eo, ca_sn_g, ca_sn_b, hstbf);
  gemm_bf<4, false><<<dim3(4, 128), 256, 0, stream>>>(
      hstbf, w_ca_so, ca_so_b, xbt, xbbf, M2, 512, 512, 512);

  // ---------- Phase C (N-split FFN: full-M dispatches) ----------
  gemm_bf<2, true><<<dim3(8, 128), 256, 0, stream>>>(
      xbbf, w_ff_l1, ff_l1_b, g1bf, nullptr, M2, 512, 512, 1024);
  gemm_bf<0, false><<<dim3(4, 128), 256, 0, stream>>>(
      g1bf, w_ff_l2, ff_l2_b, y2, nullptr, M2, 1024, 2048, 512);
  gemm_bf<2, true><<<dim3(8, 128), 256, 0, stream>>>(
      xbbf, w_ff_l1 + (size_t)1024 * 512, ff_l1_b + 1024, g1bf, nullptr, M2, 512, 512, 1024);
  gemm_bf<8, false><<<dim3(4, 128), 256, 0, stream>>>(
      g1bf, w_ff_l2 + 1024, ff_l2_b, y2, nullptr, M2, 1024, 2048, 512);
  styl_kernel<<<M2, 64, 0, stream>>>(y2, eo2, ff_sn_g, ff_sn_b, hst2bf);
  gemm_bf<5, false><<<dim3(4, 128), 256, 0, stream>>>(
      hst2bf, w_ff_so, ff_so_b, xbt, dof, M2, 512, 512, 512);
}

// Round 21
// 637.312 us; speedup vs baseline: 1.2184x; 1.0119x over previous
//
#include <hip/hip_runtime.h>
#include <hip/hip_bf16.h>
#include <cstddef>

// Problem dims
#define TT 256
#define BB 64
#define NN 77
#define DD 512
#define SS 334            // T + N + 1
#define HH 8
#define M1 (SS*BB)        // 21376
#define M2 (BB*TT)        // 16384
#define FF 2048

// Workspace: 3 regions of 10,944,512 floats each (125.25 MiB, proven OK).
#define REG 10944512ULL

typedef __attribute__((ext_vector_type(4))) float f32x4;
typedef __attribute__((ext_vector_type(8))) short bf16x8;
typedef __attribute__((ext_vector_type(8))) unsigned short u16x8;

__device__ inline unsigned short f2bf(float f) {
  __hip_bfloat16 h = __float2bfloat16(f);
  return *reinterpret_cast<unsigned short*>(&h);
}
__device__ inline float bf2f(unsigned short u) {
  return __uint_as_float(((unsigned)u) << 16);
}

// ---------------- batched f32 -> bf16 weight converter -----------------
__global__ __launch_bounds__(256) void cvt4_kernel(
    const float* s0, unsigned short* d0, int n0,
    const float* s1, unsigned short* d1, int n1,
    const float* s2, unsigned short* d2, int n2,
    const float* s3, unsigned short* d3, int n3) {
  const float* s; unsigned short* d; int n;
  switch (blockIdx.y) {
    case 0: s = s0; d = d0; n = n0; break;
    case 1: s = s1; d = d1; n = n1; break;
    case 2: s = s2; d = d2; n = n2; break;
    default: s = s3; d = d3; n = n3; break;
  }
  for (int i = (blockIdx.x * 256 + threadIdx.x) * 4; i < n; i += gridDim.x * 1024) {
    float4 v = *(const float4*)(s + i);
    ushort4 u;
    u.x = f2bf(v.x); u.y = f2bf(v.y); u.z = f2bf(v.z); u.w = f2bf(v.w);
    *(ushort4*)(d + i) = u;
  }
}

// ---------------- concat [x; xf; emb] -> src f32 (rows<TT) + bf16 ------
__global__ __launch_bounds__(256) void concat_src_kernel(
    const float* __restrict__ x, const float* __restrict__ xf,
    const float* __restrict__ emb, float* __restrict__ src,
    unsigned short* __restrict__ srcbf) {
  int idx = blockIdx.x * 256 + threadIdx.x;      // float4 index
  if (idx >= SS * BB * 128) return;
  int c4 = idx & 127;
  int row = idx >> 7;                            // s*BB + b
  int s = row >> 6, b = row & 63;
  const float* p;
  if (s < TT)            p = x   + ((size_t)(s * BB + b)) * DD;
  else if (s < TT + NN)  p = xf  + ((size_t)((s - TT) * BB + b)) * DD;
  else                   p = emb + (size_t)b * DD;
  float4 v = ((const float4*)p)[c4];
  if (s < TT)
    ((float4*)(src + (size_t)row * DD))[c4] = v;
  ushort4 u;
  u.x = f2bf(v.x); u.y = f2bf(v.y); u.z = f2bf(v.z); u.w = f2bf(v.w);
  ((ushort4*)(srcbf + (size_t)row * DD))[c4] = u;
}

// ---------------- MFMA GEMM body (all-bf16, reg-staged, BK=64) ---------
// C = epi(A[M,K]bf16 @ W[N,K]bf16^T + bias); 128x128 tile, 4 waves.
// EPI: 0 none, 1 relu, 2 gelu, 3 add-into-C(f32),
//      4 add-into-C(f32, T-MAJOR) + write bf16 copy (row-major) to C2,
//      5 out = Cp(f32 T-MAJOR read) + v, write f32 to C2 at (t*BB+b)*512+col,
//      6 fused per-64-col (head) softmax -> bf16 HEAD-MAJOR out,
//      7 scale by 0.125*log2e then bf16 out (for exp2 softmax in attn),
//      8 add-into-C(f32, row-major), NO bias.
template<int EPI, bool CBF>
__device__ __forceinline__ void gemm_body(
    unsigned short (*As)[128][8], unsigned short (*Bs)[128][8],
    const unsigned short* __restrict__ A, const unsigned short* __restrict__ W,
    const float* __restrict__ bias, void* __restrict__ Cp_, void* __restrict__ C2,
    int M, int K, int ldw, int ldc, int bxt, int byt) {
  const int tid = threadIdx.x;
  const int bm = byt * 128;
  const int bn = bxt * 128;
  const int lane = tid & 63;
  const int wave = tid >> 6;
  const int wr = wave >> 1, wc = wave & 1;
  const int q = lane >> 4, lr = lane & 15;

  f32x4 acc[4][4];
#pragma unroll
  for (int m = 0; m < 4; ++m)
#pragma unroll
    for (int n = 0; n < 4; ++n) acc[m][n] = (f32x4){0.f, 0.f, 0.f, 0.f};

  const int srow = tid >> 1;
  const int sk = (tid & 1) * 32;
  const int c0 = (tid & 1) * 4;
  int arow = bm + srow; if (arow >= M) arow = M - 1;
  const unsigned short* Ag = A + (size_t)arow * K + sk;
  const unsigned short* Wg = W + (size_t)(bn + srow) * ldw + sk;

  for (int k0 = 0; k0 < K; k0 += 64) {
    u16x8 a0 = *(const u16x8*)(Ag + k0);
    u16x8 a1 = *(const u16x8*)(Ag + k0 + 8);
    u16x8 a2 = *(const u16x8*)(Ag + k0 + 16);
    u16x8 a3 = *(const u16x8*)(Ag + k0 + 24);
    u16x8 b0 = *(const u16x8*)(Wg + k0);
    u16x8 b1 = *(const u16x8*)(Wg + k0 + 8);
    u16x8 b2 = *(const u16x8*)(Wg + k0 + 16);
    u16x8 b3 = *(const u16x8*)(Wg + k0 + 24);
    __syncthreads();
    *(u16x8*)&As[c0 + 0][srow][0] = a0;
    *(u16x8*)&As[c0 + 1][srow][0] = a1;
    *(u16x8*)&As[c0 + 2][srow][0] = a2;
    *(u16x8*)&As[c0 + 3][srow][0] = a3;
    *(u16x8*)&Bs[c0 + 0][srow][0] = b0;
    *(u16x8*)&Bs[c0 + 1][srow][0] = b1;
    *(u16x8*)&Bs[c0 + 2][srow][0] = b2;
    *(u16x8*)&Bs[c0 + 3][srow][0] = b3;
    __syncthreads();
#pragma unroll
    for (int ks = 0; ks < 2; ++ks) {
      bf16x8 af[4], bf[4];
#pragma unroll
      for (int m = 0; m < 4; ++m)
        af[m] = *(const bf16x8*)&As[ks * 4 + q][wr * 64 + m * 16 + lr][0];
#pragma unroll
      for (int n = 0; n < 4; ++n)
        bf[n] = *(const bf16x8*)&Bs[ks * 4 + q][wc * 64 + n * 16 + lr][0];
#pragma unroll
      for (int m = 0; m < 4; ++m)
#pragma unroll
        for (int n = 0; n < 4; ++n)
          acc[m][n] = __builtin_amdgcn_mfma_f32_16x16x32_bf16(af[m], bf[n], acc[m][n], 0, 0, 0);
    }
  }

  if (EPI == 6) {
    const int hcol = (bn >> 6) + wc;     // head of this wave's 64-col span
#pragma unroll
    for (int m = 0; m < 4; ++m) {
#pragma unroll
      for (int i = 0; i < 4; ++i) {
        float vv[4];
        float mx = -1e30f;
#pragma unroll
        for (int n = 0; n < 4; ++n) {
          float v = acc[m][n][i] + bias[bn + wc * 64 + n * 16 + lr];
          vv[n] = v; mx = fmaxf(mx, v);
        }
#pragma unroll
        for (int off = 8; off; off >>= 1) mx = fmaxf(mx, __shfl_xor(mx, off));
        float sum = 0.f;
#pragma unroll
        for (int n = 0; n < 4; ++n) { vv[n] = __expf(vv[n] - mx); sum += vv[n]; }
#pragma unroll
        for (int off = 8; off; off >>= 1) sum += __shfl_xor(sum, off);
        float inv = 1.f / sum;
        const int row = bm + wr * 64 + m * 16 + q * 4 + i;
        const int t = row & 255, b2 = row >> 8;
        unsigned short* dst =
            (unsigned short*)Cp_ + (((size_t)(b2 * 8 + hcol) * 256 + t) << 6);
#pragma unroll
        for (int n = 0; n < 4; ++n)
          dst[n * 16 + lr] = f2bf(vv[n] * inv);
      }
    }
    return;
  }

#pragma unroll
  for (int m = 0; m < 4; ++m) {
#pragma unroll
    for (int n = 0; n < 4; ++n) {
      const int col = bn + wc * 64 + n * 16 + lr;
      const float bb = (EPI == 8) ? 0.f : bias[col];
#pragma unroll
      for (int i = 0; i < 4; ++i) {
        const int row = bm + wr * 64 + m * 16 + q * 4 + i;
        if (row < M) {
          float v = acc[m][n][i] + bb;
          if (EPI == 1) v = fmaxf(v, 0.f);
          if (EPI == 2) v = 0.5f * v * (1.f + erff(v * 0.70710678118f));
          if (EPI == 7) v *= 0.18033688011f;   // 0.125 * log2(e)
          if (EPI <= 2 || EPI == 7) {
            if (CBF) ((unsigned short*)Cp_)[(size_t)row * ldc + col] = f2bf(v);
            else     ((float*)Cp_)[(size_t)row * ldc + col] = v;
          } else if (EPI == 3 || EPI == 8) {
            ((float*)Cp_)[(size_t)row * ldc + col] += v;
          } else if (EPI == 4) {
            const int t = row & 255, b2 = row >> 8;
            float* C = (float*)Cp_ + ((size_t)(t * BB + b2)) * DD + col;
            float o = *C + v; *C = o;
            ((unsigned short*)C2)[(size_t)row * ldc + col] = f2bf(o);
          } else {  // EPI == 5
            const int t = row & 255, b2 = row >> 8;
            const size_t idx = ((size_t)(t * BB + b2)) * DD + col;
            float o = ((const float*)Cp_)[idx] + v;
            ((float*)C2)[idx] = o;
          }
        }
      }
    }
  }
}

// ---------------- single-op GEMM kernel (with XCD swizzle) -------------
template<int EPI, bool CBF>
__global__ __launch_bounds__(256) void gemm_bf(
    const unsigned short* __restrict__ A, const unsigned short* __restrict__ W,
    const float* __restrict__ bias, void* __restrict__ Cp_, void* __restrict__ C2,
    int M, int K, int ldw, int ldc) {
  __shared__ unsigned short As[8][128][8];
  __shared__ unsigned short Bs[8][128][8];
  int bxt, byt;
  {
    int total = gridDim.x * gridDim.y;
    int raw = blockIdx.y * gridDim.x + blockIdx.x;
    if ((total & 7) == 0) {
      int lid = (raw & 7) * (total >> 3) + (raw >> 3);
      bxt = lid % gridDim.x;
      byt = lid / gridDim.x;
    } else { bxt = blockIdx.x; byt = blockIdx.y; }
  }
  gemm_body<EPI, CBF>(As, Bs, A, W, bias, Cp_, C2, M, K, ldw, ldc, bxt, byt);
}

// ---------------- dual-op GEMM kernel (two independent GEMMs) ----------
// op0 occupies blockIdx.x < gx0 (rows < gy0); op1 the rest (full gridDim.y).
template<int EPI0, bool CBF0, int EPI1, bool CBF1>
__global__ __launch_bounds__(256) void gemm_dual(
    const unsigned short* __restrict__ A0, const unsigned short* __restrict__ W0,
    const float* __restrict__ bias0, void* __restrict__ C0,
    int M0, int K0, int ldw0, int ldc0, int gx0, int gy0,
    const unsigned short* __restrict__ A1, const unsigned short* __restrict__ W1,
    const float* __restrict__ bias1, void* __restrict__ C1,
    int Mb, int K1, int ldw1, int ldc1) {
  __shared__ unsigned short As[8][128][8];
  __shared__ unsigned short Bs[8][128][8];
  if ((int)blockIdx.x < gx0) {
    if ((int)blockIdx.y >= gy0) return;
    gemm_body<EPI0, CBF0>(As, Bs, A0, W0, bias0, C0, nullptr,
                          M0, K0, ldw0, ldc0, blockIdx.x, blockIdx.y);
  } else {
    gemm_body<EPI1, CBF1>(As, Bs, A1, W1, bias1, C1, nullptr,
                          Mb, K1, ldw1, ldc1, blockIdx.x - gx0, blockIdx.y);
  }
}

// ---------------- MFMA flash attention: 128 queries per block ----------
// Q pre-scaled by 0.125*log2e -> use exp2f (hardware-native, identical math).
__global__ __launch_bounds__(256) void attn_mfma_kernel(
    const unsigned short* __restrict__ Qb, const unsigned short* __restrict__ KVb,
    unsigned short* __restrict__ Ob) {
  __shared__ unsigned short Qs[128][72];
  __shared__ unsigned short Ks[64][72];
  __shared__ unsigned short Vt[64][72];
  __shared__ unsigned short Ps[4][16][72];
  const int bh = blockIdx.y, b = bh >> 3, h = bh & 7;
  const int s0 = blockIdx.x << 7;
  const int tid = threadIdx.x;
  const int wave = tid >> 6, lane = tid & 63;
  const int q = lane >> 4, lr = lane & 15;
  const int sr = tid >> 2;
  const int c0 = (tid & 3) << 4;
#pragma unroll
  for (int it = 0; it < 4; ++it) {
    int v = it * 256 + tid;
    int row = v >> 3, col = (v & 7) * 8;
    u16x8 d8 = *(const u16x8*)(Qb + ((size_t)((s0 + row) * BB + b)) * 512 + h * 64 + col);
    *(u16x8*)&Qs[row][col] = d8;
  }
  f32x4 oacc[2][4];
#pragma unroll
  for (int m = 0; m < 2; ++m)
#pragma unroll
    for (int dt = 0; dt < 4; ++dt) oacc[m][dt] = (f32x4){0.f, 0.f, 0.f, 0.f};
  float m_r[2][4], l_r[2][4];
#pragma unroll
  for (int m = 0; m < 2; ++m)
#pragma unroll
    for (int i = 0; i < 4; ++i) { m_r[m][i] = -1e30f; l_r[m][i] = 0.f; }

  for (int kt = 0; kt < 6; ++kt) {
    __syncthreads();
    {
      int t = kt * 64 + sr;
      u16x8 k0 = {0, 0, 0, 0, 0, 0, 0, 0}, k1 = k0, w0 = k0, w1 = k0;
      if (t < SS) {
        const unsigned short* kp = KVb + ((size_t)(t * BB + b)) * 1024 + h * 64 + c0;
        k0 = *(const u16x8*)kp; k1 = *(const u16x8*)(kp + 8);
        w0 = *(const u16x8*)(kp + 512); w1 = *(const u16x8*)(kp + 520);
      }
      *(u16x8*)&Ks[sr][c0] = k0;
      *(u16x8*)&Ks[sr][c0 + 8] = k1;
#pragma unroll
      for (int j = 0; j < 8; ++j) Vt[c0 + j][sr] = w0[j];
#pragma unroll
      for (int j = 0; j < 8; ++j) Vt[c0 + 8 + j][sr] = w1[j];
    }
    __syncthreads();
#pragma unroll
    for (int m = 0; m < 2; ++m) {
      f32x4 sacc[4];
#pragma unroll
      for (int ct = 0; ct < 4; ++ct) sacc[ct] = (f32x4){0.f, 0.f, 0.f, 0.f};
#pragma unroll
      for (int kc = 0; kc < 2; ++kc) {
        bf16x8 aq = *(const bf16x8*)&Qs[wave * 32 + m * 16 + lr][kc * 32 + q * 8];
#pragma unroll
        for (int ct = 0; ct < 4; ++ct) {
          bf16x8 bk = *(const bf16x8*)&Ks[ct * 16 + lr][kc * 32 + q * 8];
          sacc[ct] = __builtin_amdgcn_mfma_f32_16x16x32_bf16(aq, bk, sacc[ct], 0, 0, 0);
        }
      }
      if (kt == 5) {
#pragma unroll
        for (int ct = 0; ct < 4; ++ct)
          if (320 + ct * 16 + lr >= SS) {
#pragma unroll
            for (int i = 0; i < 4; ++i) sacc[ct][i] = -1e30f;
          }
      }
      float pexp[4][4];
#pragma unroll
      for (int i = 0; i < 4; ++i) {
        float mt = fmaxf(fmaxf(sacc[0][i], sacc[1][i]), fmaxf(sacc[2][i], sacc[3][i]));
#pragma unroll
        for (int off = 8; off; off >>= 1) mt = fmaxf(mt, __shfl_xor(mt, off));
        float mn = fmaxf(m_r[m][i], mt);
        float rescale = exp2f(m_r[m][i] - mn);
        m_r[m][i] = mn;
        float se = 0.f;
#pragma unroll
        for (int ct = 0; ct < 4; ++ct) {
          float e = exp2f(sacc[ct][i] - mn);
          pexp[ct][i] = e;
          se += e;
        }
#pragma unroll
        for (int off = 8; off; off >>= 1) se += __shfl_xor(se, off);
        l_r[m][i] = l_r[m][i] * rescale + se;
#pragma unroll
        for (int dt = 0; dt < 4; ++dt) oacc[m][dt][i] *= rescale;
      }
#pragma unroll
      for (int ct = 0; ct < 4; ++ct)
#pragma unroll
        for (int i = 0; i < 4; ++i)
          Ps[wave][q * 4 + i][ct * 16 + lr] = f2bf(pexp[ct][i]);
#pragma unroll
      for (int kc = 0; kc < 2; ++kc) {
        bf16x8 ap = *(const bf16x8*)&Ps[wave][lr][kc * 32 + q * 8];
#pragma unroll
        for (int dt = 0; dt < 4; ++dt) {
          bf16x8 bv = *(const bf16x8*)&Vt[dt * 16 + lr][kc * 32 + q * 8];
          oacc[m][dt] = __builtin_amdgcn_mfma_f32_16x16x32_bf16(ap, bv, oacc[m][dt], 0, 0, 0);
        }
      }
    }
  }
#pragma unroll
  for (int m = 0; m < 2; ++m) {
#pragma unroll
    for (int i = 0; i < 4; ++i) {
      int s = s0 + wave * 32 + m * 16 + q * 4 + i;
      float inv = 1.f / l_r[m][i];
      unsigned short* op = Ob + ((size_t)(s * BB + b)) * 512 + h * 64;
#pragma unroll
      for (int dt = 0; dt < 4; ++dt)
        op[dt * 16 + lr] = f2bf(oacc[m][dt][i] * inv);
    }
  }
}

// ------- MFMA linear-attn PV -------------------------------------------
__global__ __launch_bounds__(256) void lin_y_mfma(
    const unsigned short* __restrict__ qch, const unsigned short* __restrict__ ctxT,
    float* __restrict__ y) {
  __shared__ unsigned short Qs[256][72];
  __shared__ unsigned short Cs[64][72];
  const int bh = blockIdx.x, b = bh >> 3, h = bh & 7;
  const int tid = threadIdx.x;
  const int wave = tid >> 6, lane = tid & 63;
  const int q = lane >> 4, lr = lane & 15;
  {
    const unsigned short* qp = qch + (size_t)bh * 16384;
#pragma unroll
    for (int it = 0; it < 8; ++it) {
      int v = it * 256 + tid;
      u16x8 d8 = *(const u16x8*)(qp + v * 8);
      *(u16x8*)&Qs[v >> 3][(v & 7) * 8] = d8;
    }
    const unsigned short* cp = ctxT + (size_t)bh * 4096;
#pragma unroll
    for (int it = 0; it < 2; ++it) {
      int v = it * 256 + tid;
      u16x8 d8 = *(const u16x8*)(cp + v * 8);
      *(u16x8*)&Cs[v >> 3][(v & 7) * 8] = d8;
    }
  }
  __syncthreads();
  f32x4 acc[4][4];
#pragma unroll
  for (int m = 0; m < 4; ++m)
#pragma unroll
    for (int n = 0; n < 4; ++n) acc[m][n] = (f32x4){0.f, 0.f, 0.f, 0.f};
#pragma unroll
  for (int kc = 0; kc < 2; ++kc) {
    bf16x8 af[4], bf[4];
#pragma unroll
    for (int m = 0; m < 4; ++m)
      af[m] = *(const bf16x8*)&Qs[wave * 64 + m * 16 + lr][kc * 32 + q * 8];
#pragma unroll
    for (int n = 0; n < 4; ++n)
      bf[n] = *(const bf16x8*)&Cs[n * 16 + lr][kc * 32 + q * 8];
#pragma unroll
    for (int m = 0; m < 4; ++m)
#pragma unroll
      for (int n = 0; n < 4; ++n)
        acc[m][n] = __builtin_amdgcn_mfma_f32_16x16x32_bf16(af[m], bf[n], acc[m][n], 0, 0, 0);
  }
#pragma unroll
  for (int m = 0; m < 4; ++m) {
#pragma unroll
    for (int n = 0; n < 4; ++n) {
#pragma unroll
      for (int i = 0; i < 4; ++i) {
        int t = wave * 64 + m * 16 + q * 4 + i;
        y[((size_t)(b * TT + t)) * DD + h * 64 + n * 16 + lr] = acc[m][n][i];
      }
    }
  }
}

// ------- fused silu + both stylization emb linears (eo, eo2) -----------
__global__ __launch_bounds__(256) void gemm_se_kernel(
    const float* __restrict__ emb,
    const float* __restrict__ w0, const float* __restrict__ b0, float* __restrict__ c0_,
    const float* __restrict__ w1, const float* __restrict__ b1, float* __restrict__ c1_) {
  __shared__ float As[16][64];
  __shared__ float Ws[16][64];
  const float* W    = blockIdx.y ? w1 : w0;
  const float* bias = blockIdx.y ? b1 : b0;
  float* C          = blockIdx.y ? c1_ : c0_;
  const int tid = threadIdx.x;
  const int bn = blockIdx.x << 6;
  const int lr = tid >> 2;
  const int lk = (tid & 3) << 2;
  const float* Ap = emb + (size_t)lr * 512 + lk;
  const float* Wp = W + (size_t)(bn + lr) * 512 + lk;
  const int tx = tid & 15, ty = tid >> 4;
  float c[4][4] = {};
  for (int k0 = 0; k0 < 512; k0 += 16) {
    float4 av = *(const float4*)(Ap + k0);
    av.x = av.x / (1.f + __expf(-av.x));
    av.y = av.y / (1.f + __expf(-av.y));
    av.z = av.z / (1.f + __expf(-av.z));
    av.w = av.w / (1.f + __expf(-av.w));
    float4 wv = *(const float4*)(Wp + k0);
    __syncthreads();
    As[lk + 0][lr] = av.x; As[lk + 1][lr] = av.y;
    As[lk + 2][lr] = av.z; As[lk + 3][lr] = av.w;
    Ws[lk + 0][lr] = wv.x; Ws[lk + 1][lr] = wv.y;
    Ws[lk + 2][lr] = wv.z; Ws[lk + 3][lr] = wv.w;
    __syncthreads();
#pragma unroll
    for (int k = 0; k < 16; ++k) {
      const float4 a = *(const float4*)&As[k][ty << 2];
      const float4 w = *(const float4*)&Ws[k][tx << 2];
      c[0][0] += a.x * w.x; c[0][1] += a.x * w.y; c[0][2] += a.x * w.z; c[0][3] += a.x * w.w;
      c[1][0] += a.y * w.x; c[1][1] += a.y * w.y; c[1][2] += a.y * w.z; c[1][3] += a.y * w.w;
      c[2][0] += a.z * w.x; c[2][1] += a.z * w.y; c[2][2] += a.z * w.z; c[2][3] += a.z * w.w;
      c[3][0] += a.w * w.x; c[3][1] += a.w * w.y; c[3][2] += a.w * w.z; c[3][3] += a.w * w.w;
    }
  }
#pragma unroll
  for (int i = 0; i < 4; ++i) {
    int row = (ty << 2) + i;
    float* Cp = C + (size_t)row * 1024 + bn + (tx << 2);
#pragma unroll
    for (int j = 0; j < 4; ++j)
      Cp[j] = c[i][j] + bias[bn + (tx << 2) + j];
  }
}

// ---------------- LayerNorm row kernel: f32 out + optional bf16 out ----
__global__ __launch_bounds__(64) void ln_kernel(
    const float* __restrict__ in, const float* __restrict__ res,
    float* __restrict__ out, const float* __restrict__ g,
    const float* __restrict__ beta, unsigned short* __restrict__ obf) {
  const int row = blockIdx.x;
  const int lane = threadIdx.x;
  const float* ip = in + (size_t)row * DD;
  float v[8];
  float s = 0.f, ss = 0.f;
#pragma unroll
  for (int u = 0; u < 2; ++u) {
    int d = u * 256 + lane * 4;
    float4 a = *(const float4*)(ip + d);
    if (res) {
      float4 r = *(const float4*)(res + (size_t)row * DD + d);
      a.x += r.x; a.y += r.y; a.z += r.z; a.w += r.w;
    }
    v[u * 4 + 0] = a.x; v[u * 4 + 1] = a.y; v[u * 4 + 2] = a.z; v[u * 4 + 3] = a.w;
    s += a.x + a.y + a.z + a.w;
    ss += a.x * a.x + a.y * a.y + a.z * a.z + a.w * a.w;
  }
#pragma unroll
  for (int off = 32; off; off >>= 1) { s += __shfl_xor(s, off); ss += __shfl_xor(ss, off); }
  float mean = s * (1.f / 512.f);
  float var = ss * (1.f / 512.f) - mean * mean;
  float rstd = rsqrtf(var + 1e-5f);
  float* op = out + (size_t)row * DD;
#pragma unroll
  for (int u = 0; u < 2; ++u) {
    int d = u * 256 + lane * 4;
    float4 o4;
    o4.x = (v[u * 4 + 0] - mean) * rstd * g[d + 0] + beta[d + 0];
    o4.y = (v[u * 4 + 1] - mean) * rstd * g[d + 1] + beta[d + 1];
    o4.z = (v[u * 4 + 2] - mean) * rstd * g[d + 2] + beta[d + 2];
    o4.w = (v[u * 4 + 3] - mean) * rstd * g[d + 3] + beta[d + 3];
    *(float4*)(op + d) = o4;
    if (obf) {
      ushort4 u4;
      u4.x = f2bf(o4.x); u4.y = f2bf(o4.y); u4.z = f2bf(o4.z); u4.w = f2bf(o4.w);
      *(ushort4*)(obf + (size_t)row * DD + d) = u4;
    }
  }
}

// ------- fused residual-LN (IN-PLACE, t-major) + second LN (bf16 out) --
__global__ __launch_bounds__(64) void t2bln_res_kernel(
    float* __restrict__ src, const float* __restrict__ proj2,
    unsigned short* __restrict__ xnbf,
    const float* __restrict__ g2, const float* __restrict__ b2,
    const float* __restrict__ gca, const float* __restrict__ bca) {
  const int row = blockIdx.x;          // t*BB + b
  const int t = row >> 6, b = row & 63;
  const size_t soff = (size_t)row * DD;
  const int lane = threadIdx.x;
  float v[8];
  float s = 0.f, ss = 0.f;
#pragma unroll
  for (int u = 0; u < 2; ++u) {
    int d = u * 256 + lane * 4;
    float4 a = *(const float4*)(src + soff + d);
    float4 r = *(const float4*)(proj2 + soff + d);
    a.x += r.x; a.y += r.y; a.z += r.z; a.w += r.w;
    v[u * 4 + 0] = a.x; v[u * 4 + 1] = a.y; v[u * 4 + 2] = a.z; v[u * 4 + 3] = a.w;
    s += a.x + a.y + a.z + a.w;
    ss += a.x * a.x + a.y * a.y + a.z * a.z + a.w * a.w;
  }
#pragma unroll
  for (int off = 32; off; off >>= 1) { s += __shfl_xor(s, off); ss += __shfl_xor(ss, off); }
  float mean = s * (1.f / 512.f);
  float var = ss * (1.f / 512.f) - mean * mean;
  float rstd = rsqrtf(var + 1e-5f);
  float s2 = 0.f, ss2 = 0.f;
#pragma unroll
  for (int u = 0; u < 8; ++u) {
    int d = (u >> 2) * 256 + lane * 4 + (u & 3);
    float o = (v[u] - mean) * rstd * g2[d] + b2[d];
    v[u] = o;
    s2 += o; ss2 += o * o;
  }
#pragma unroll
  for (int u = 0; u < 2; ++u) {
    int d = u * 256 + lane * 4;
    float4 o4 = {v[u * 4 + 0], v[u * 4 + 1], v[u * 4 + 2], v[u * 4 + 3]};
    *(float4*)(src + soff + d) = o4;
  }
#pragma unroll
  for (int off = 32; off; off >>= 1) { s2 += __shfl_xor(s2, off); ss2 += __shfl_xor(ss2, off); }
  float mean2 = s2 * (1.f / 512.f);
  float var2 = ss2 * (1.f / 512.f) - mean2 * mean2;
  float rstd2 = rsqrtf(var2 + 1e-5f);
  const size_t orow = (size_t)(b * TT + t) * DD;
#pragma unroll
  for (int u = 0; u < 2; ++u) {
    int d = u * 256 + lane * 4;
    ushort4 u4;
    u4.x = f2bf((v[u * 4 + 0] - mean2) * rstd2 * gca[d + 0] + bca[d + 0]);
    u4.y = f2bf((v[u * 4 + 1] - mean2) * rstd2 * gca[d + 1] + bca[d + 1]);
    u4.z = f2bf((v[u * 4 + 2] - mean2) * rstd2 * gca[d + 2] + bca[d + 2]);
    u4.w = f2bf((v[u * 4 + 3] - mean2) * rstd2 * gca[d + 3] + bca[d + 3]);
    *(ushort4*)(xnbf + orow + d) = u4;
  }
}

// ------- fused transpose + LN (xf path) --------------------------------
__global__ __launch_bounds__(64) void t2bln_kernel(
    const float* __restrict__ in, unsigned short* __restrict__ obf,
    const float* __restrict__ g, const float* __restrict__ beta, int Rr) {
  const int rp = blockIdx.x;
  const int b = rp / Rr, r = rp % Rr;
  const float* ip = in + ((size_t)(r * BB + b)) * DD;
  const int lane = threadIdx.x;
  float v[8];
  float s = 0.f, ss = 0.f;
#pragma unroll
  for (int u = 0; u < 2; ++u) {
    int d = u * 256 + lane * 4;
    float4 a = *(const float4*)(ip + d);
    v[u * 4 + 0] = a.x; v[u * 4 + 1] = a.y; v[u * 4 + 2] = a.z; v[u * 4 + 3] = a.w;
    s += a.x + a.y + a.z + a.w;
    ss += a.x * a.x + a.y * a.y + a.z * a.z + a.w * a.w;
  }
#pragma unroll
  for (int off = 32; off; off >>= 1) { s += __shfl_xor(s, off); ss += __shfl_xor(ss, off); }
  float mean = s * (1.f / 512.f);
  float var = ss * (1.f / 512.f) - mean * mean;
  float rstd = rsqrtf(var + 1e-5f);
#pragma unroll
  for (int u = 0; u < 2; ++u) {
    int d = u * 256 + lane * 4;
    ushort4 u4;
    u4.x = f2bf((v[u * 4 + 0] - mean) * rstd * g[d + 0] + beta[d + 0]);
    u4.y = f2bf((v[u * 4 + 1] - mean) * rstd * g[d + 1] + beta[d + 1]);
    u4.z = f2bf((v[u * 4 + 2] - mean) * rstd * g[d + 2] + beta[d + 2]);
    u4.w = f2bf((v[u * 4 + 3] - mean) * rstd * g[d + 3] + beta[d + 3]);
    *(ushort4*)(obf + (size_t)rp * DD + d) = u4;
  }
}

// ---------------- stylization: silu(LN(y)*(1+scale)+shift) -> bf16 -----
__global__ __launch_bounds__(64) void styl_kernel(
    const float* __restrict__ y, const float* __restrict__ eo,
    const float* __restrict__ g, const float* __restrict__ beta,
    unsigned short* __restrict__ out) {
  const int row = blockIdx.x;         // b*TT + t
  const int b = row >> 8;
  const int lane = threadIdx.x;
  const float* ip = y + (size_t)row * DD;
  const float* sc = eo + (size_t)b * 1024;
  float v[8];
  float s = 0.f, ss = 0.f;
#pragma unroll
  for (int u = 0; u < 2; ++u) {
    int d = u * 256 + lane * 4;
    float4 a = *(const float4*)(ip + d);
    v[u * 4 + 0] = a.x; v[u * 4 + 1] = a.y; v[u * 4 + 2] = a.z; v[u * 4 + 3] = a.w;
    s += a.x + a.y + a.z + a.w;
    ss += a.x * a.x + a.y * a.y + a.z * a.z + a.w * a.w;
  }
#pragma unroll
  for (int off = 32; off; off >>= 1) { s += __shfl_xor(s, off); ss += __shfl_xor(ss, off); }
  float mean = s * (1.f / 512.f);
  float var = ss * (1.f / 512.f) - mean * mean;
  float rstd = rsqrtf(var + 1e-5f);
#pragma unroll
  for (int u = 0; u < 2; ++u) {
    int d0 = u * 256 + lane * 4;
    ushort4 u4;
#pragma unroll
    for (int j = 0; j < 4; ++j) {
      int d = d0 + j;
      float ln = (v[u * 4 + j] - mean) * rstd * g[d] + beta[d];
      float h = ln * (1.f + sc[d]) + sc[512 + d];
      float r = h / (1.f + __expf(-h));
      ((unsigned short*)&u4)[j] = f2bf(r);
    }
    *(ushort4*)(out + (size_t)row * DD + d0) = u4;
  }
}

// ---------------- softmax over n (kc, axis=1, 77 tokens) ---------------
__global__ __launch_bounds__(256) void softmax_n_kernel(float* __restrict__ a) {
  int b = blockIdx.x;
  int c = blockIdx.y * 256 + threadIdx.x;
  float* p = a + ((size_t)b * NN) * DD + c;
  float m = -1e30f;
  for (int n = 0; n < NN; ++n) m = fmaxf(m, p[(size_t)n * DD]);
  float sum = 0.f;
  for (int n = 0; n < NN; ++n) sum += __expf(p[(size_t)n * DD] - m);
  float inv = 1.f / sum;
  for (int n = 0; n < NN; ++n) p[(size_t)n * DD] = __expf(p[(size_t)n * DD] - m) * inv;
}

// ------- ctx: ctxT[bh][l][d] (bf16) = sum_n kc[b,n,h,d]*vc[b,n,h,l] ----
__global__ __launch_bounds__(256) void ctx_kernel(
    const float* __restrict__ kc, const float* __restrict__ vc,
    unsigned short* __restrict__ ctxT) {
  __shared__ float ks[NN][64];
  __shared__ float vs[NN][64];
  int bh = blockIdx.x; int b = bh >> 3, h = bh & 7;
  for (int l = threadIdx.x; l < NN * 64; l += 256) {
    int n = l >> 6, d = l & 63;
    size_t idx = ((size_t)(b * NN + n)) * DD + h * 64 + d;
    ks[n][d] = kc[idx];
    vs[n][d] = vc[idx];
  }
  __syncthreads();
  int d = threadIdx.x >> 2;
  int l0 = (threadIdx.x & 3) << 4;
  float acc[16] = {};
  for (int n = 0; n < NN; ++n) {
    float kd = ks[n][d];
#pragma unroll
    for (int j = 0; j < 16; ++j) acc[j] += kd * vs[n][l0 + j];
  }
  unsigned short* cp = ctxT + (size_t)bh * 4096 + d;
#pragma unroll
  for (int j = 0; j < 16; ++j) cp[(size_t)(l0 + j) * 64] = f2bf(acc[j]);
}

extern "C" void kernel_launch(void* const* d_in, const int* in_sizes, int n_in,
                              void* d_out, int out_size, void* d_ws, size_t ws_size,
                              hipStream_t stream) {
  const float* x       = (const float*)d_in[0];
  const float* xf      = (const float*)d_in[1];
  const float* emb     = (const float*)d_in[2];
  const float* sa_in_w = (const float*)d_in[3];
  const float* sa_in_b = (const float*)d_in[4];
  const float* sa_out_w= (const float*)d_in[5];
  const float* sa_out_b= (const float*)d_in[6];
  const float* sa_l1_w = (const float*)d_in[7];
  const float* sa_l1_b = (const float*)d_in[8];
  const float* sa_l2_w = (const float*)d_in[9];
  const float* sa_l2_b = (const float*)d_in[10];
  const float* sa_n1_g = (const float*)d_in[11];
  const float* sa_n1_b = (const float*)d_in[12];
  const float* sa_n2_g = (const float*)d_in[13];
  const float* sa_n2_b = (const float*)d_in[14];
  const float* ca_norm_g = (const float*)d_in[15];
  const float* ca_norm_b = (const float*)d_in[16];
  const float* ca_tnorm_g= (const float*)d_in[17];
  const float* ca_tnorm_b= (const float*)d_in[18];
  const float* ca_q_w  = (const float*)d_in[19];
  const float* ca_q_b  = (const float*)d_in[20];
  const float* ca_k_w  = (const float*)d_in[21];
  const float* ca_k_b  = (const float*)d_in[22];
  const float* ca_v_w  = (const float*)d_in[23];
  const float* ca_v_b  = (const float*)d_in[24];
  const float* ca_se_w = (const float*)d_in[25];
  const float* ca_se_b = (const float*)d_in[26];
  const float* ca_sn_g = (const float*)d_in[27];
  const float* ca_sn_b = (const float*)d_in[28];
  const float* ca_so_w = (const float*)d_in[29];
  const float* ca_so_b = (const float*)d_in[30];
  const float* ff_l1_w = (const float*)d_in[31];
  const float* ff_l1_b = (const float*)d_in[32];
  const float* ff_l2_w = (const float*)d_in[33];
  const float* ff_l2_b = (const float*)d_in[34];
  const float* ff_se_w = (const float*)d_in[35];
  const float* ff_se_b = (const float*)d_in[36];
  const float* ff_sn_g = (const float*)d_in[37];
  const float* ff_sn_b = (const float*)d_in[38];
  const float* ff_so_w = (const float*)d_in[39];
  const float* ff_so_b = (const float*)d_in[40];

  float* R1 = (float*)d_ws;
  float* R2 = R1 + REG;
  float* R3 = R2 + REG;
  float* dof = (float*)d_out;

  // bf16 weight slots
  unsigned short* w_sa_in  = (unsigned short*)dof;
  unsigned short* w_sa_out = w_sa_in + 786432;
  unsigned short* w_sa_l1  = w_sa_out + 262144;
  unsigned short* w_sa_l2  = w_sa_l1 + 524288;
  unsigned short* srcbf    = (unsigned short*)(dof + 1048576);
  unsigned short* w_ca_q  = (unsigned short*)(R2 + 8552448);
  unsigned short* w_ca_k  = w_ca_q + 262144;
  unsigned short* w_ca_v  = w_ca_k + 262144;
  unsigned short* w_ca_so = w_ca_v + 262144;
  unsigned short* w_ff_l1 = (unsigned short*)(R2 + 9076736);
  unsigned short* w_ff_l2 = w_ff_l1 + 1048576;
  unsigned short* w_ff_so = w_ff_l2 + 1048576;

  // Phase A aliases
  float* src = R1;
  unsigned short* Qbf  = (unsigned short*)R3;
  unsigned short* Obf  = (unsigned short*)(R3 + 5472256);
  unsigned short* KVbf = (unsigned short*)R2;
  float* proj  = R2;
  unsigned short* h1bf = (unsigned short*)R2;
  float* proj2 = R3;
  float* xbt = R1;
  // Phase B aliases
  unsigned short* xnbf = (unsigned short*)R2;
  unsigned short* tnbf = (unsigned short*)(R2 + 4194304);
  unsigned short* qch = (unsigned short*)dof;
  float* kc  = R3;
  float* vc  = R3 + 2523136;
  unsigned short* ctxTbf = (unsigned short*)(R3 + 5046272);
  unsigned short* hstbf = (unsigned short*)(R3 + 6094848);
  unsigned short* xbbf  = (unsigned short*)(R3 + 8192000);
  float* eo  = R2 + 8421376;
  float* eo2 = eo + 65536;
  float* yb  = R2;
  // Phase C aliases
  unsigned short* g1bf = (unsigned short*)R2;
  float* y2 = dof;
  unsigned short* hst2bf = (unsigned short*)R3;

  // ---------- Phase A ----------
  cvt4_kernel<<<dim3(1024, 4), 256, 0, stream>>>(
      sa_in_w, w_sa_in, 786432, sa_out_w, w_sa_out, 262144,
      sa_l1_w, w_sa_l1, 524288, sa_l2_w, w_sa_l2, 524288);
  concat_src_kernel<<<10688, 256, 0, stream>>>(x, xf, emb, src, srcbf);
  // merged: Q-proj (EPI7, grid 4x128) + KV-proj (EPI0, grid 8x167)
  gemm_dual<7, true, 0, true><<<dim3(12, 167), 256, 0, stream>>>(
      srcbf, w_sa_in, sa_in_b, Qbf, M2, 512, 512, 512, 4, 128,
      srcbf, w_sa_in + (size_t)512 * 512, sa_in_b + 512, KVbf, M1, 512, 512, 1024);
  attn_mfma_kernel<<<dim3(2, BB * HH), 256, 0, stream>>>(Qbf, KVbf, Obf);
  gemm_bf<0, false><<<dim3(4, 128), 256, 0, stream>>>(
      Obf, w_sa_out, sa_out_b, proj, nullptr, M2, 512, 512, 512);
  ln_kernel<<<M2, 64, 0, stream>>>(src, proj, src, sa_n1_g, sa_n1_b, srcbf);
  gemm_bf<1, true><<<dim3(8, 128), 256, 0, stream>>>(
      srcbf, w_sa_l1, sa_l1_b, h1bf, nullptr, M2, 512, 512, 1024);
  gemm_bf<0, false><<<dim3(4, 128), 256, 0, stream>>>(
      h1bf, w_sa_l2, sa_l2_b, proj2, nullptr, M2, 1024, 1024, 512);
  cvt4_kernel<<<dim3(1024, 4), 256, 0, stream>>>(
      ca_q_w, w_ca_q, 262144, ca_k_w, w_ca_k, 262144,
      ca_v_w, w_ca_v, 262144, ca_so_w, w_ca_so, 262144);
  cvt4_kernel<<<dim3(1024, 4), 256, 0, stream>>>(
      ff_l1_w, w_ff_l1, 1048576, ff_l2_w, w_ff_l2, 1048576,
      ff_so_w, w_ff_so, 262144, nullptr, nullptr, 0);
  t2bln_res_kernel<<<M2, 64, 0, stream>>>(
      src, proj2, xnbf, sa_n2_g, sa_n2_b, ca_norm_g, ca_norm_b);

  // ---------- Phase B ----------
  gemm_bf<6, false><<<dim3(4, 128), 256, 0, stream>>>(
      xnbf, w_ca_q, ca_q_b, qch, nullptr, M2, 512, 512, 512);
  t2bln_kernel<<<BB * NN, 64, 0, stream>>>(xf, tnbf, ca_tnorm_g, ca_tnorm_b, NN);
  // merged: ca_k + ca_v (both grid 4x39, same A)
  gemm_dual<0, false, 0, false><<<dim3(8, 39), 256, 0, stream>>>(
      tnbf, w_ca_k, ca_k_b, kc, BB * NN, 512, 512, 512, 4, 39,
      tnbf, w_ca_v, ca_v_b, vc, BB * NN, 512, 512, 512);
  softmax_n_kernel<<<dim3(64, 2), 256, 0, stream>>>(kc);
  ctx_kernel<<<BB * HH, 256, 0, stream>>>(kc, vc, ctxTbf);
  gemm_se_kernel<<<dim3(16, 2), 256, 0, stream>>>(
      emb, ca_se_w, ca_se_b, eo, ff_se_w, ff_se_b, eo2);
  lin_y_mfma<<<BB * HH, 256, 0, stream>>>(qch, ctxTbf, yb);
  styl_kernel<<<M2, 64, 0, stream>>>(yb, eo, ca_sn_g, ca_sn_b, hstbf);
  gemm_bf<4, false><<<dim3(4, 128), 256, 0, stream>>>(
      hstbf, w_ca_so, ca_so_b, xbt, xbbf, M2, 512, 512, 512);

  // ---------- Phase C (N-split FFN: full-M dispatches) ----------
  gemm_bf<2, true><<<dim3(8, 128), 256, 0, stream>>>(
      xbbf, w_ff_l1, ff_l1_b, g1bf, nullptr, M2, 512, 512, 1024);
  gemm_bf<0, false><<<dim3(4, 128), 256, 0, stream>>>(
      g1bf, w_ff_l2, ff_l2_b, y2, nullptr, M2, 1024, 2048, 512);
  gemm_bf<2, true><<<dim3(8, 128), 256, 0, stream>>>(
      xbbf, w_ff_l1 + (size_t)1024 * 512, ff_l1_b + 1024, g1bf, nullptr, M2, 512, 512, 1024);
  gemm_bf<8, false><<<dim3(4, 128), 256, 0, stream>>>(
      g1bf, w_ff_l2 + 1024, ff_l2_b, y2, nullptr, M2, 1024, 2048, 512);
  styl_kernel<<<M2, 64, 0, stream>>>(y2, eo2, ff_sn_g, ff_sn_b, hst2bf);
  gemm_bf<5, false><<<dim3(4, 128), 256, 0, stream>>>(
      hst2bf, w_ff_so, ff_so_b, xbt, dof, M2, 512, 512, 512);
}

// Round 22
// 624.673 us; speedup vs baseline: 1.2431x; 1.0202x over previous
//
#include <hip/hip_runtime.h>
#include <hip/hip_bf16.h>
#include <cstddef>

// Problem dims
#define TT 256
#define BB 64
#define NN 77
#define DD 512
#define SS 334            // T + N + 1
#define HH 8
#define M1 (SS*BB)        // 21376
#define M2 (BB*TT)        // 16384
#define FF 2048

// Workspace: 3 regions of 10,944,512 floats each (125.25 MiB, proven OK).
#define REG 10944512ULL

typedef __attribute__((ext_vector_type(4))) float f32x4;
typedef __attribute__((ext_vector_type(8))) short bf16x8;
typedef __attribute__((ext_vector_type(8))) unsigned short u16x8;

__device__ inline unsigned short f2bf(float f) {
  __hip_bfloat16 h = __float2bfloat16(f);
  return *reinterpret_cast<unsigned short*>(&h);
}
__device__ inline float bf2f(unsigned short u) {
  return __uint_as_float(((unsigned)u) << 16);
}

// ---------------- batched f32 -> bf16 weight converter -----------------
__global__ __launch_bounds__(256) void cvt4_kernel(
    const float* s0, unsigned short* d0, int n0,
    const float* s1, unsigned short* d1, int n1,
    const float* s2, unsigned short* d2, int n2,
    const float* s3, unsigned short* d3, int n3) {
  const float* s; unsigned short* d; int n;
  switch (blockIdx.y) {
    case 0: s = s0; d = d0; n = n0; break;
    case 1: s = s1; d = d1; n = n1; break;
    case 2: s = s2; d = d2; n = n2; break;
    default: s = s3; d = d3; n = n3; break;
  }
  for (int i = (blockIdx.x * 256 + threadIdx.x) * 4; i < n; i += gridDim.x * 1024) {
    float4 v = *(const float4*)(s + i);
    ushort4 u;
    u.x = f2bf(v.x); u.y = f2bf(v.y); u.z = f2bf(v.z); u.w = f2bf(v.w);
    *(ushort4*)(d + i) = u;
  }
}

// ---------------- concat [x; xf; emb] -> src f32 (rows<TT) + bf16 ------
__global__ __launch_bounds__(256) void concat_src_kernel(
    const float* __restrict__ x, const float* __restrict__ xf,
    const float* __restrict__ emb, float* __restrict__ src,
    unsigned short* __restrict__ srcbf) {
  int idx = blockIdx.x * 256 + threadIdx.x;      // float4 index
  if (idx >= SS * BB * 128) return;
  int c4 = idx & 127;
  int row = idx >> 7;                            // s*BB + b
  int s = row >> 6, b = row & 63;
  const float* p;
  if (s < TT)            p = x   + ((size_t)(s * BB + b)) * DD;
  else if (s < TT + NN)  p = xf  + ((size_t)((s - TT) * BB + b)) * DD;
  else                   p = emb + (size_t)b * DD;
  float4 v = ((const float4*)p)[c4];
  if (s < TT)
    ((float4*)(src + (size_t)row * DD))[c4] = v;
  ushort4 u;
  u.x = f2bf(v.x); u.y = f2bf(v.y); u.z = f2bf(v.z); u.w = f2bf(v.w);
  ((ushort4*)(srcbf + (size_t)row * DD))[c4] = u;
}

// ---------------- MFMA GEMM body (all-bf16, reg-staged, BK=64) ---------
// C = epi(A[M,K]bf16 @ W[N,K]bf16^T + bias); 128x128 tile, 4 waves.
// EPI: 0 none, 1 relu, 2 gelu, 3 add-into-C(f32),
//      4 add-into-C(f32, T-MAJOR) + write bf16 copy (row-major) to C2,
//      5 out = Cp(f32 T-MAJOR read) + v, write f32 to C2 at (t*BB+b)*512+col,
//      6 fused per-64-col (head) softmax -> bf16 HEAD-MAJOR out,
//      7 scale by 0.125 then bf16 out (attn Q prescale),
//      8 add-into-C(f32, row-major), NO bias.
template<int EPI, bool CBF>
__device__ __forceinline__ void gemm_body(
    unsigned short (*As)[128][8], unsigned short (*Bs)[128][8],
    const unsigned short* __restrict__ A, const unsigned short* __restrict__ W,
    const float* __restrict__ bias, void* __restrict__ Cp_, void* __restrict__ C2,
    int M, int K, int ldw, int ldc, int bxt, int byt) {
  const int tid = threadIdx.x;
  const int bm = byt * 128;
  const int bn = bxt * 128;
  const int lane = tid & 63;
  const int wave = tid >> 6;
  const int wr = wave >> 1, wc = wave & 1;
  const int q = lane >> 4, lr = lane & 15;

  f32x4 acc[4][4];
#pragma unroll
  for (int m = 0; m < 4; ++m)
#pragma unroll
    for (int n = 0; n < 4; ++n) acc[m][n] = (f32x4){0.f, 0.f, 0.f, 0.f};

  const int srow = tid >> 1;
  const int sk = (tid & 1) * 32;
  const int c0 = (tid & 1) * 4;
  int arow = bm + srow; if (arow >= M) arow = M - 1;
  const unsigned short* Ag = A + (size_t)arow * K + sk;
  const unsigned short* Wg = W + (size_t)(bn + srow) * ldw + sk;

  for (int k0 = 0; k0 < K; k0 += 64) {
    u16x8 a0 = *(const u16x8*)(Ag + k0);
    u16x8 a1 = *(const u16x8*)(Ag + k0 + 8);
    u16x8 a2 = *(const u16x8*)(Ag + k0 + 16);
    u16x8 a3 = *(const u16x8*)(Ag + k0 + 24);
    u16x8 b0 = *(const u16x8*)(Wg + k0);
    u16x8 b1 = *(const u16x8*)(Wg + k0 + 8);
    u16x8 b2 = *(const u16x8*)(Wg + k0 + 16);
    u16x8 b3 = *(const u16x8*)(Wg + k0 + 24);
    __syncthreads();
    *(u16x8*)&As[c0 + 0][srow][0] = a0;
    *(u16x8*)&As[c0 + 1][srow][0] = a1;
    *(u16x8*)&As[c0 + 2][srow][0] = a2;
    *(u16x8*)&As[c0 + 3][srow][0] = a3;
    *(u16x8*)&Bs[c0 + 0][srow][0] = b0;
    *(u16x8*)&Bs[c0 + 1][srow][0] = b1;
    *(u16x8*)&Bs[c0 + 2][srow][0] = b2;
    *(u16x8*)&Bs[c0 + 3][srow][0] = b3;
    __syncthreads();
#pragma unroll
    for (int ks = 0; ks < 2; ++ks) {
      bf16x8 af[4], bf[4];
#pragma unroll
      for (int m = 0; m < 4; ++m)
        af[m] = *(const bf16x8*)&As[ks * 4 + q][wr * 64 + m * 16 + lr][0];
#pragma unroll
      for (int n = 0; n < 4; ++n)
        bf[n] = *(const bf16x8*)&Bs[ks * 4 + q][wc * 64 + n * 16 + lr][0];
#pragma unroll
      for (int m = 0; m < 4; ++m)
#pragma unroll
        for (int n = 0; n < 4; ++n)
          acc[m][n] = __builtin_amdgcn_mfma_f32_16x16x32_bf16(af[m], bf[n], acc[m][n], 0, 0, 0);
    }
  }

  if (EPI == 6) {
    const int hcol = (bn >> 6) + wc;     // head of this wave's 64-col span
#pragma unroll
    for (int m = 0; m < 4; ++m) {
#pragma unroll
      for (int i = 0; i < 4; ++i) {
        float vv[4];
        float mx = -1e30f;
#pragma unroll
        for (int n = 0; n < 4; ++n) {
          float v = acc[m][n][i] + bias[bn + wc * 64 + n * 16 + lr];
          vv[n] = v; mx = fmaxf(mx, v);
        }
#pragma unroll
        for (int off = 8; off; off >>= 1) mx = fmaxf(mx, __shfl_xor(mx, off));
        float sum = 0.f;
#pragma unroll
        for (int n = 0; n < 4; ++n) { vv[n] = __expf(vv[n] - mx); sum += vv[n]; }
#pragma unroll
        for (int off = 8; off; off >>= 1) sum += __shfl_xor(sum, off);
        float inv = 1.f / sum;
        const int row = bm + wr * 64 + m * 16 + q * 4 + i;
        const int t = row & 255, b2 = row >> 8;
        unsigned short* dst =
            (unsigned short*)Cp_ + (((size_t)(b2 * 8 + hcol) * 256 + t) << 6);
#pragma unroll
        for (int n = 0; n < 4; ++n)
          dst[n * 16 + lr] = f2bf(vv[n] * inv);
      }
    }
    return;
  }

#pragma unroll
  for (int m = 0; m < 4; ++m) {
#pragma unroll
    for (int n = 0; n < 4; ++n) {
      const int col = bn + wc * 64 + n * 16 + lr;
      const float bb = (EPI == 8) ? 0.f : bias[col];
#pragma unroll
      for (int i = 0; i < 4; ++i) {
        const int row = bm + wr * 64 + m * 16 + q * 4 + i;
        if (row < M) {
          float v = acc[m][n][i] + bb;
          if (EPI == 1) v = fmaxf(v, 0.f);
          if (EPI == 2) v = 0.5f * v * (1.f + erff(v * 0.70710678118f));
          if (EPI == 7) v *= 0.125f;
          if (EPI <= 2 || EPI == 7) {
            if (CBF) ((unsigned short*)Cp_)[(size_t)row * ldc + col] = f2bf(v);
            else     ((float*)Cp_)[(size_t)row * ldc + col] = v;
          } else if (EPI == 3 || EPI == 8) {
            ((float*)Cp_)[(size_t)row * ldc + col] += v;
          } else if (EPI == 4) {
            const int t = row & 255, b2 = row >> 8;
            float* C = (float*)Cp_ + ((size_t)(t * BB + b2)) * DD + col;
            float o = *C + v; *C = o;
            ((unsigned short*)C2)[(size_t)row * ldc + col] = f2bf(o);
          } else {  // EPI == 5
            const int t = row & 255, b2 = row >> 8;
            const size_t idx = ((size_t)(t * BB + b2)) * DD + col;
            float o = ((const float*)Cp_)[idx] + v;
            ((float*)C2)[idx] = o;
          }
        }
      }
    }
  }
}

// ---------------- single-op GEMM kernel (with XCD swizzle) -------------
template<int EPI, bool CBF>
__global__ __launch_bounds__(256) void gemm_bf(
    const unsigned short* __restrict__ A, const unsigned short* __restrict__ W,
    const float* __restrict__ bias, void* __restrict__ Cp_, void* __restrict__ C2,
    int M, int K, int ldw, int ldc) {
  __shared__ unsigned short As[8][128][8];
  __shared__ unsigned short Bs[8][128][8];
  int bxt, byt;
  {
    int total = gridDim.x * gridDim.y;
    int raw = blockIdx.y * gridDim.x + blockIdx.x;
    if ((total & 7) == 0) {
      int lid = (raw & 7) * (total >> 3) + (raw >> 3);
      bxt = lid % gridDim.x;
      byt = lid / gridDim.x;
    } else { bxt = blockIdx.x; byt = blockIdx.y; }
  }
  gemm_body<EPI, CBF>(As, Bs, A, W, bias, Cp_, C2, M, K, ldw, ldc, bxt, byt);
}

// ---------------- dual-op GEMM kernel (two independent GEMMs) ----------
// op0 occupies blockIdx.x < gx0 (rows < gy0); op1 the rest (full gridDim.y).
template<int EPI0, bool CBF0, int EPI1, bool CBF1>
__global__ __launch_bounds__(256) void gemm_dual(
    const unsigned short* __restrict__ A0, const unsigned short* __restrict__ W0,
    const float* __restrict__ bias0, void* __restrict__ C0,
    int M0, int K0, int ldw0, int ldc0, int gx0, int gy0,
    const unsigned short* __restrict__ A1, const unsigned short* __restrict__ W1,
    const float* __restrict__ bias1, void* __restrict__ C1,
    int Mb, int K1, int ldw1, int ldc1) {
  __shared__ unsigned short As[8][128][8];
  __shared__ unsigned short Bs[8][128][8];
  if ((int)blockIdx.x < gx0) {
    if ((int)blockIdx.y >= gy0) return;
    gemm_body<EPI0, CBF0>(As, Bs, A0, W0, bias0, C0, nullptr,
                          M0, K0, ldw0, ldc0, blockIdx.x, blockIdx.y);
  } else {
    gemm_body<EPI1, CBF1>(As, Bs, A1, W1, bias1, C1, nullptr,
                          Mb, K1, ldw1, ldc1, blockIdx.x - gx0, blockIdx.y);
  }
}

// ---------------- MFMA flash attention: 128 queries per block ----------
// Q pre-scaled by 0.125; softmax via __expf (fast-path intrinsic).
__global__ __launch_bounds__(256) void attn_mfma_kernel(
    const unsigned short* __restrict__ Qb, const unsigned short* __restrict__ KVb,
    unsigned short* __restrict__ Ob) {
  __shared__ unsigned short Qs[128][72];
  __shared__ unsigned short Ks[64][72];
  __shared__ unsigned short Vt[64][72];
  __shared__ unsigned short Ps[4][16][72];
  const int bh = blockIdx.y, b = bh >> 3, h = bh & 7;
  const int s0 = blockIdx.x << 7;
  const int tid = threadIdx.x;
  const int wave = tid >> 6, lane = tid & 63;
  const int q = lane >> 4, lr = lane & 15;
  const int sr = tid >> 2;
  const int c0 = (tid & 3) << 4;
#pragma unroll
  for (int it = 0; it < 4; ++it) {
    int v = it * 256 + tid;
    int row = v >> 3, col = (v & 7) * 8;
    u16x8 d8 = *(const u16x8*)(Qb + ((size_t)((s0 + row) * BB + b)) * 512 + h * 64 + col);
    *(u16x8*)&Qs[row][col] = d8;
  }
  f32x4 oacc[2][4];
#pragma unroll
  for (int m = 0; m < 2; ++m)
#pragma unroll
    for (int dt = 0; dt < 4; ++dt) oacc[m][dt] = (f32x4){0.f, 0.f, 0.f, 0.f};
  float m_r[2][4], l_r[2][4];
#pragma unroll
  for (int m = 0; m < 2; ++m)
#pragma unroll
    for (int i = 0; i < 4; ++i) { m_r[m][i] = -1e30f; l_r[m][i] = 0.f; }

  for (int kt = 0; kt < 6; ++kt) {
    __syncthreads();
    {
      int t = kt * 64 + sr;
      u16x8 k0 = {0, 0, 0, 0, 0, 0, 0, 0}, k1 = k0, w0 = k0, w1 = k0;
      if (t < SS) {
        const unsigned short* kp = KVb + ((size_t)(t * BB + b)) * 1024 + h * 64 + c0;
        k0 = *(const u16x8*)kp; k1 = *(const u16x8*)(kp + 8);
        w0 = *(const u16x8*)(kp + 512); w1 = *(const u16x8*)(kp + 520);
      }
      *(u16x8*)&Ks[sr][c0] = k0;
      *(u16x8*)&Ks[sr][c0 + 8] = k1;
#pragma unroll
      for (int j = 0; j < 8; ++j) Vt[c0 + j][sr] = w0[j];
#pragma unroll
      for (int j = 0; j < 8; ++j) Vt[c0 + 8 + j][sr] = w1[j];
    }
    __syncthreads();
#pragma unroll
    for (int m = 0; m < 2; ++m) {
      f32x4 sacc[4];
#pragma unroll
      for (int ct = 0; ct < 4; ++ct) sacc[ct] = (f32x4){0.f, 0.f, 0.f, 0.f};
#pragma unroll
      for (int kc = 0; kc < 2; ++kc) {
        bf16x8 aq = *(const bf16x8*)&Qs[wave * 32 + m * 16 + lr][kc * 32 + q * 8];
#pragma unroll
        for (int ct = 0; ct < 4; ++ct) {
          bf16x8 bk = *(const bf16x8*)&Ks[ct * 16 + lr][kc * 32 + q * 8];
          sacc[ct] = __builtin_amdgcn_mfma_f32_16x16x32_bf16(aq, bk, sacc[ct], 0, 0, 0);
        }
      }
      if (kt == 5) {
#pragma unroll
        for (int ct = 0; ct < 4; ++ct)
          if (320 + ct * 16 + lr >= SS) {
#pragma unroll
            for (int i = 0; i < 4; ++i) sacc[ct][i] = -1e30f;
          }
      }
      float pexp[4][4];
#pragma unroll
      for (int i = 0; i < 4; ++i) {
        float mt = fmaxf(fmaxf(sacc[0][i], sacc[1][i]), fmaxf(sacc[2][i], sacc[3][i]));
#pragma unroll
        for (int off = 8; off; off >>= 1) mt = fmaxf(mt, __shfl_xor(mt, off));
        float mn = fmaxf(m_r[m][i], mt);
        float rescale = __expf(m_r[m][i] - mn);
        m_r[m][i] = mn;
        float se = 0.f;
#pragma unroll
        for (int ct = 0; ct < 4; ++ct) {
          float e = __expf(sacc[ct][i] - mn);
          pexp[ct][i] = e;
          se += e;
        }
#pragma unroll
        for (int off = 8; off; off >>= 1) se += __shfl_xor(se, off);
        l_r[m][i] = l_r[m][i] * rescale + se;
#pragma unroll
        for (int dt = 0; dt < 4; ++dt) oacc[m][dt][i] *= rescale;
      }
#pragma unroll
      for (int ct = 0; ct < 4; ++ct)
#pragma unroll
        for (int i = 0; i < 4; ++i)
          Ps[wave][q * 4 + i][ct * 16 + lr] = f2bf(pexp[ct][i]);
#pragma unroll
      for (int kc = 0; kc < 2; ++kc) {
        bf16x8 ap = *(const bf16x8*)&Ps[wave][lr][kc * 32 + q * 8];
#pragma unroll
        for (int dt = 0; dt < 4; ++dt) {
          bf16x8 bv = *(const bf16x8*)&Vt[dt * 16 + lr][kc * 32 + q * 8];
          oacc[m][dt] = __builtin_amdgcn_mfma_f32_16x16x32_bf16(ap, bv, oacc[m][dt], 0, 0, 0);
        }
      }
    }
  }
#pragma unroll
  for (int m = 0; m < 2; ++m) {
#pragma unroll
    for (int i = 0; i < 4; ++i) {
      int s = s0 + wave * 32 + m * 16 + q * 4 + i;
      float inv = 1.f / l_r[m][i];
      unsigned short* op = Ob + ((size_t)(s * BB + b)) * 512 + h * 64;
#pragma unroll
      for (int dt = 0; dt < 4; ++dt)
        op[dt * 16 + lr] = f2bf(oacc[m][dt][i] * inv);
    }
  }
}

// ------- MFMA linear-attn PV -------------------------------------------
__global__ __launch_bounds__(256) void lin_y_mfma(
    const unsigned short* __restrict__ qch, const unsigned short* __restrict__ ctxT,
    float* __restrict__ y) {
  __shared__ unsigned short Qs[256][72];
  __shared__ unsigned short Cs[64][72];
  const int bh = blockIdx.x, b = bh >> 3, h = bh & 7;
  const int tid = threadIdx.x;
  const int wave = tid >> 6, lane = tid & 63;
  const int q = lane >> 4, lr = lane & 15;
  {
    const unsigned short* qp = qch + (size_t)bh * 16384;
#pragma unroll
    for (int it = 0; it < 8; ++it) {
      int v = it * 256 + tid;
      u16x8 d8 = *(const u16x8*)(qp + v * 8);
      *(u16x8*)&Qs[v >> 3][(v & 7) * 8] = d8;
    }
    const unsigned short* cp = ctxT + (size_t)bh * 4096;
#pragma unroll
    for (int it = 0; it < 2; ++it) {
      int v = it * 256 + tid;
      u16x8 d8 = *(const u16x8*)(cp + v * 8);
      *(u16x8*)&Cs[v >> 3][(v & 7) * 8] = d8;
    }
  }
  __syncthreads();
  f32x4 acc[4][4];
#pragma unroll
  for (int m = 0; m < 4; ++m)
#pragma unroll
    for (int n = 0; n < 4; ++n) acc[m][n] = (f32x4){0.f, 0.f, 0.f, 0.f};
#pragma unroll
  for (int kc = 0; kc < 2; ++kc) {
    bf16x8 af[4], bf[4];
#pragma unroll
    for (int m = 0; m < 4; ++m)
      af[m] = *(const bf16x8*)&Qs[wave * 64 + m * 16 + lr][kc * 32 + q * 8];
#pragma unroll
    for (int n = 0; n < 4; ++n)
      bf[n] = *(const bf16x8*)&Cs[n * 16 + lr][kc * 32 + q * 8];
#pragma unroll
    for (int m = 0; m < 4; ++m)
#pragma unroll
      for (int n = 0; n < 4; ++n)
        acc[m][n] = __builtin_amdgcn_mfma_f32_16x16x32_bf16(af[m], bf[n], acc[m][n], 0, 0, 0);
  }
#pragma unroll
  for (int m = 0; m < 4; ++m) {
#pragma unroll
    for (int n = 0; n < 4; ++n) {
#pragma unroll
      for (int i = 0; i < 4; ++i) {
        int t = wave * 64 + m * 16 + q * 4 + i;
        y[((size_t)(b * TT + t)) * DD + h * 64 + n * 16 + lr] = acc[m][n][i];
      }
    }
  }
}

// ------- fused silu + both stylization emb linears (eo, eo2) -----------
__global__ __launch_bounds__(256) void gemm_se_kernel(
    const float* __restrict__ emb,
    const float* __restrict__ w0, const float* __restrict__ b0, float* __restrict__ c0_,
    const float* __restrict__ w1, const float* __restrict__ b1, float* __restrict__ c1_) {
  __shared__ float As[16][64];
  __shared__ float Ws[16][64];
  const float* W    = blockIdx.y ? w1 : w0;
  const float* bias = blockIdx.y ? b1 : b0;
  float* C          = blockIdx.y ? c1_ : c0_;
  const int tid = threadIdx.x;
  const int bn = blockIdx.x << 6;
  const int lr = tid >> 2;
  const int lk = (tid & 3) << 2;
  const float* Ap = emb + (size_t)lr * 512 + lk;
  const float* Wp = W + (size_t)(bn + lr) * 512 + lk;
  const int tx = tid & 15, ty = tid >> 4;
  float c[4][4] = {};
  for (int k0 = 0; k0 < 512; k0 += 16) {
    float4 av = *(const float4*)(Ap + k0);
    av.x = av.x / (1.f + __expf(-av.x));
    av.y = av.y / (1.f + __expf(-av.y));
    av.z = av.z / (1.f + __expf(-av.z));
    av.w = av.w / (1.f + __expf(-av.w));
    float4 wv = *(const float4*)(Wp + k0);
    __syncthreads();
    As[lk + 0][lr] = av.x; As[lk + 1][lr] = av.y;
    As[lk + 2][lr] = av.z; As[lk + 3][lr] = av.w;
    Ws[lk + 0][lr] = wv.x; Ws[lk + 1][lr] = wv.y;
    Ws[lk + 2][lr] = wv.z; Ws[lk + 3][lr] = wv.w;
    __syncthreads();
#pragma unroll
    for (int k = 0; k < 16; ++k) {
      const float4 a = *(const float4*)&As[k][ty << 2];
      const float4 w = *(const float4*)&Ws[k][tx << 2];
      c[0][0] += a.x * w.x; c[0][1] += a.x * w.y; c[0][2] += a.x * w.z; c[0][3] += a.x * w.w;
      c[1][0] += a.y * w.x; c[1][1] += a.y * w.y; c[1][2] += a.y * w.z; c[1][3] += a.y * w.w;
      c[2][0] += a.z * w.x; c[2][1] += a.z * w.y; c[2][2] += a.z * w.z; c[2][3] += a.z * w.w;
      c[3][0] += a.w * w.x; c[3][1] += a.w * w.y; c[3][2] += a.w * w.z; c[3][3] += a.w * w.w;
    }
  }
#pragma unroll
  for (int i = 0; i < 4; ++i) {
    int row = (ty << 2) + i;
    float* Cp = C + (size_t)row * 1024 + bn + (tx << 2);
#pragma unroll
    for (int j = 0; j < 4; ++j)
      Cp[j] = c[i][j] + bias[bn + (tx << 2) + j];
  }
}

// ---------------- LayerNorm row kernel: f32 out + optional bf16 out ----
__global__ __launch_bounds__(64) void ln_kernel(
    const float* __restrict__ in, const float* __restrict__ res,
    float* __restrict__ out, const float* __restrict__ g,
    const float* __restrict__ beta, unsigned short* __restrict__ obf) {
  const int row = blockIdx.x;
  const int lane = threadIdx.x;
  const float* ip = in + (size_t)row * DD;
  float v[8];
  float s = 0.f, ss = 0.f;
#pragma unroll
  for (int u = 0; u < 2; ++u) {
    int d = u * 256 + lane * 4;
    float4 a = *(const float4*)(ip + d);
    if (res) {
      float4 r = *(const float4*)(res + (size_t)row * DD + d);
      a.x += r.x; a.y += r.y; a.z += r.z; a.w += r.w;
    }
    v[u * 4 + 0] = a.x; v[u * 4 + 1] = a.y; v[u * 4 + 2] = a.z; v[u * 4 + 3] = a.w;
    s += a.x + a.y + a.z + a.w;
    ss += a.x * a.x + a.y * a.y + a.z * a.z + a.w * a.w;
  }
#pragma unroll
  for (int off = 32; off; off >>= 1) { s += __shfl_xor(s, off); ss += __shfl_xor(ss, off); }
  float mean = s * (1.f / 512.f);
  float var = ss * (1.f / 512.f) - mean * mean;
  float rstd = rsqrtf(var + 1e-5f);
  float* op = out + (size_t)row * DD;
#pragma unroll
  for (int u = 0; u < 2; ++u) {
    int d = u * 256 + lane * 4;
    float4 o4;
    o4.x = (v[u * 4 + 0] - mean) * rstd * g[d + 0] + beta[d + 0];
    o4.y = (v[u * 4 + 1] - mean) * rstd * g[d + 1] + beta[d + 1];
    o4.z = (v[u * 4 + 2] - mean) * rstd * g[d + 2] + beta[d + 2];
    o4.w = (v[u * 4 + 3] - mean) * rstd * g[d + 3] + beta[d + 3];
    *(float4*)(op + d) = o4;
    if (obf) {
      ushort4 u4;
      u4.x = f2bf(o4.x); u4.y = f2bf(o4.y); u4.z = f2bf(o4.z); u4.w = f2bf(o4.w);
      *(ushort4*)(obf + (size_t)row * DD + d) = u4;
    }
  }
}

// ------- fused residual-LN (IN-PLACE, t-major) + second LN (bf16 out) --
__global__ __launch_bounds__(64) void t2bln_res_kernel(
    float* __restrict__ src, const float* __restrict__ proj2,
    unsigned short* __restrict__ xnbf,
    const float* __restrict__ g2, const float* __restrict__ b2,
    const float* __restrict__ gca, const float* __restrict__ bca) {
  const int row = blockIdx.x;          // t*BB + b
  const int t = row >> 6, b = row & 63;
  const size_t soff = (size_t)row * DD;
  const int lane = threadIdx.x;
  float v[8];
  float s = 0.f, ss = 0.f;
#pragma unroll
  for (int u = 0; u < 2; ++u) {
    int d = u * 256 + lane * 4;
    float4 a = *(const float4*)(src + soff + d);
    float4 r = *(const float4*)(proj2 + soff + d);
    a.x += r.x; a.y += r.y; a.z += r.z; a.w += r.w;
    v[u * 4 + 0] = a.x; v[u * 4 + 1] = a.y; v[u * 4 + 2] = a.z; v[u * 4 + 3] = a.w;
    s += a.x + a.y + a.z + a.w;
    ss += a.x * a.x + a.y * a.y + a.z * a.z + a.w * a.w;
  }
#pragma unroll
  for (int off = 32; off; off >>= 1) { s += __shfl_xor(s, off); ss += __shfl_xor(ss, off); }
  float mean = s * (1.f / 512.f);
  float var = ss * (1.f / 512.f) - mean * mean;
  float rstd = rsqrtf(var + 1e-5f);
  float s2 = 0.f, ss2 = 0.f;
#pragma unroll
  for (int u = 0; u < 8; ++u) {
    int d = (u >> 2) * 256 + lane * 4 + (u & 3);
    float o = (v[u] - mean) * rstd * g2[d] + b2[d];
    v[u] = o;
    s2 += o; ss2 += o * o;
  }
#pragma unroll
  for (int u = 0; u < 2; ++u) {
    int d = u * 256 + lane * 4;
    float4 o4 = {v[u * 4 + 0], v[u * 4 + 1], v[u * 4 + 2], v[u * 4 + 3]};
    *(float4*)(src + soff + d) = o4;
  }
#pragma unroll
  for (int off = 32; off; off >>= 1) { s2 += __shfl_xor(s2, off); ss2 += __shfl_xor(ss2, off); }
  float mean2 = s2 * (1.f / 512.f);
  float var2 = ss2 * (1.f / 512.f) - mean2 * mean2;
  float rstd2 = rsqrtf(var2 + 1e-5f);
  const size_t orow = (size_t)(b * TT + t) * DD;
#pragma unroll
  for (int u = 0; u < 2; ++u) {
    int d = u * 256 + lane * 4;
    ushort4 u4;
    u4.x = f2bf((v[u * 4 + 0] - mean2) * rstd2 * gca[d + 0] + bca[d + 0]);
    u4.y = f2bf((v[u * 4 + 1] - mean2) * rstd2 * gca[d + 1] + bca[d + 1]);
    u4.z = f2bf((v[u * 4 + 2] - mean2) * rstd2 * gca[d + 2] + bca[d + 2]);
    u4.w = f2bf((v[u * 4 + 3] - mean2) * rstd2 * gca[d + 3] + bca[d + 3]);
    *(ushort4*)(xnbf + orow + d) = u4;
  }
}

// ------- fused transpose + LN (xf path) --------------------------------
__global__ __launch_bounds__(64) void t2bln_kernel(
    const float* __restrict__ in, unsigned short* __restrict__ obf,
    const float* __restrict__ g, const float* __restrict__ beta, int Rr) {
  const int rp = blockIdx.x;
  const int b = rp / Rr, r = rp % Rr;
  const float* ip = in + ((size_t)(r * BB + b)) * DD;
  const int lane = threadIdx.x;
  float v[8];
  float s = 0.f, ss = 0.f;
#pragma unroll
  for (int u = 0; u < 2; ++u) {
    int d = u * 256 + lane * 4;
    float4 a = *(const float4*)(ip + d);
    v[u * 4 + 0] = a.x; v[u * 4 + 1] = a.y; v[u * 4 + 2] = a.z; v[u * 4 + 3] = a.w;
    s += a.x + a.y + a.z + a.w;
    ss += a.x * a.x + a.y * a.y + a.z * a.z + a.w * a.w;
  }
#pragma unroll
  for (int off = 32; off; off >>= 1) { s += __shfl_xor(s, off); ss += __shfl_xor(ss, off); }
  float mean = s * (1.f / 512.f);
  float var = ss * (1.f / 512.f) - mean * mean;
  float rstd = rsqrtf(var + 1e-5f);
#pragma unroll
  for (int u = 0; u < 2; ++u) {
    int d = u * 256 + lane * 4;
    ushort4 u4;
    u4.x = f2bf((v[u * 4 + 0] - mean) * rstd * g[d + 0] + beta[d + 0]);
    u4.y = f2bf((v[u * 4 + 1] - mean) * rstd * g[d + 1] + beta[d + 1]);
    u4.z = f2bf((v[u * 4 + 2] - mean) * rstd * g[d + 2] + beta[d + 2]);
    u4.w = f2bf((v[u * 4 + 3] - mean) * rstd * g[d + 3] + beta[d + 3]);
    *(ushort4*)(obf + (size_t)rp * DD + d) = u4;
  }
}

// ---------------- stylization: silu(LN(y)*(1+scale)+shift) -> bf16 -----
__global__ __launch_bounds__(64) void styl_kernel(
    const float* __restrict__ y, const float* __restrict__ eo,
    const float* __restrict__ g, const float* __restrict__ beta,
    unsigned short* __restrict__ out) {
  const int row = blockIdx.x;         // b*TT + t
  const int b = row >> 8;
  const int lane = threadIdx.x;
  const float* ip = y + (size_t)row * DD;
  const float* sc = eo + (size_t)b * 1024;
  float v[8];
  float s = 0.f, ss = 0.f;
#pragma unroll
  for (int u = 0; u < 2; ++u) {
    int d = u * 256 + lane * 4;
    float4 a = *(const float4*)(ip + d);
    v[u * 4 + 0] = a.x; v[u * 4 + 1] = a.y; v[u * 4 + 2] = a.z; v[u * 4 + 3] = a.w;
    s += a.x + a.y + a.z + a.w;
    ss += a.x * a.x + a.y * a.y + a.z * a.z + a.w * a.w;
  }
#pragma unroll
  for (int off = 32; off; off >>= 1) { s += __shfl_xor(s, off); ss += __shfl_xor(ss, off); }
  float mean = s * (1.f / 512.f);
  float var = ss * (1.f / 512.f) - mean * mean;
  float rstd = rsqrtf(var + 1e-5f);
#pragma unroll
  for (int u = 0; u < 2; ++u) {
    int d0 = u * 256 + lane * 4;
    ushort4 u4;
#pragma unroll
    for (int j = 0; j < 4; ++j) {
      int d = d0 + j;
      float ln = (v[u * 4 + j] - mean) * rstd * g[d] + beta[d];
      float h = ln * (1.f + sc[d]) + sc[512 + d];
      float r = h / (1.f + __expf(-h));
      ((unsigned short*)&u4)[j] = f2bf(r);
    }
    *(ushort4*)(out + (size_t)row * DD + d0) = u4;
  }
}

// ---------------- softmax over n (kc, axis=1, 77 tokens) ---------------
__global__ __launch_bounds__(256) void softmax_n_kernel(float* __restrict__ a) {
  int b = blockIdx.x;
  int c = blockIdx.y * 256 + threadIdx.x;
  float* p = a + ((size_t)b * NN) * DD + c;
  float m = -1e30f;
  for (int n = 0; n < NN; ++n) m = fmaxf(m, p[(size_t)n * DD]);
  float sum = 0.f;
  for (int n = 0; n < NN; ++n) sum += __expf(p[(size_t)n * DD] - m);
  float inv = 1.f / sum;
  for (int n = 0; n < NN; ++n) p[(size_t)n * DD] = __expf(p[(size_t)n * DD] - m) * inv;
}

// ------- ctx: ctxT[bh][l][d] (bf16) = sum_n kc[b,n,h,d]*vc[b,n,h,l] ----
__global__ __launch_bounds__(256) void ctx_kernel(
    const float* __restrict__ kc, const float* __restrict__ vc,
    unsigned short* __restrict__ ctxT) {
  __shared__ float ks[NN][64];
  __shared__ float vs[NN][64];
  int bh = blockIdx.x; int b = bh >> 3, h = bh & 7;
  for (int l = threadIdx.x; l < NN * 64; l += 256) {
    int n = l >> 6, d = l & 63;
    size_t idx = ((size_t)(b * NN + n)) * DD + h * 64 + d;
    ks[n][d] = kc[idx];
    vs[n][d] = vc[idx];
  }
  __syncthreads();
  int d = threadIdx.x >> 2;
  int l0 = (threadIdx.x & 3) << 4;
  float acc[16] = {};
  for (int n = 0; n < NN; ++n) {
    float kd = ks[n][d];
#pragma unroll
    for (int j = 0; j < 16; ++j) acc[j] += kd * vs[n][l0 + j];
  }
  unsigned short* cp = ctxT + (size_t)bh * 4096 + d;
#pragma unroll
  for (int j = 0; j < 16; ++j) cp[(size_t)(l0 + j) * 64] = f2bf(acc[j]);
}

extern "C" void kernel_launch(void* const* d_in, const int* in_sizes, int n_in,
                              void* d_out, int out_size, void* d_ws, size_t ws_size,
                              hipStream_t stream) {
  const float* x       = (const float*)d_in[0];
  const float* xf      = (const float*)d_in[1];
  const float* emb     = (const float*)d_in[2];
  const float* sa_in_w = (const float*)d_in[3];
  const float* sa_in_b = (const float*)d_in[4];
  const float* sa_out_w= (const float*)d_in[5];
  const float* sa_out_b= (const float*)d_in[6];
  const float* sa_l1_w = (const float*)d_in[7];
  const float* sa_l1_b = (const float*)d_in[8];
  const float* sa_l2_w = (const float*)d_in[9];
  const float* sa_l2_b = (const float*)d_in[10];
  const float* sa_n1_g = (const float*)d_in[11];
  const float* sa_n1_b = (const float*)d_in[12];
  const float* sa_n2_g = (const float*)d_in[13];
  const float* sa_n2_b = (const float*)d_in[14];
  const float* ca_norm_g = (const float*)d_in[15];
  const float* ca_norm_b = (const float*)d_in[16];
  const float* ca_tnorm_g= (const float*)d_in[17];
  const float* ca_tnorm_b= (const float*)d_in[18];
  const float* ca_q_w  = (const float*)d_in[19];
  const float* ca_q_b  = (const float*)d_in[20];
  const float* ca_k_w  = (const float*)d_in[21];
  const float* ca_k_b  = (const float*)d_in[22];
  const float* ca_v_w  = (const float*)d_in[23];
  const float* ca_v_b  = (const float*)d_in[24];
  const float* ca_se_w = (const float*)d_in[25];
  const float* ca_se_b = (const float*)d_in[26];
  const float* ca_sn_g = (const float*)d_in[27];
  const float* ca_sn_b = (const float*)d_in[28];
  const float* ca_so_w = (const float*)d_in[29];
  const float* ca_so_b = (const float*)d_in[30];
  const float* ff_l1_w = (const float*)d_in[31];
  const float* ff_l1_b = (const float*)d_in[32];
  const float* ff_l2_w = (const float*)d_in[33];
  const float* ff_l2_b = (const float*)d_in[34];
  const float* ff_se_w = (const float*)d_in[35];
  const float* ff_se_b = (const float*)d_in[36];
  const float* ff_sn_g = (const float*)d_in[37];
  const float* ff_sn_b = (const float*)d_in[38];
  const float* ff_so_w = (const float*)d_in[39];
  const float* ff_so_b = (const float*)d_in[40];

  float* R1 = (float*)d_ws;
  float* R2 = R1 + REG;
  float* R3 = R2 + REG;
  float* dof = (float*)d_out;

  // bf16 weight slots
  unsigned short* w_sa_in  = (unsigned short*)dof;
  unsigned short* w_sa_out = w_sa_in + 786432;
  unsigned short* w_sa_l1  = w_sa_out + 262144;
  unsigned short* w_sa_l2  = w_sa_l1 + 524288;
  unsigned short* srcbf    = (unsigned short*)(dof + 1048576);
  unsigned short* w_ca_q  = (unsigned short*)(R2 + 8552448);
  unsigned short* w_ca_k  = w_ca_q + 262144;
  unsigned short* w_ca_v  = w_ca_k + 262144;
  unsigned short* w_ca_so = w_ca_v + 262144;
  unsigned short* w_ff_l1 = (unsigned short*)(R2 + 9076736);
  unsigned short* w_ff_l2 = w_ff_l1 + 1048576;
  unsigned short* w_ff_so = w_ff_l2 + 1048576;

  // Phase A aliases
  float* src = R1;
  unsigned short* Qbf  = (unsigned short*)R3;
  unsigned short* Obf  = (unsigned short*)(R3 + 5472256);
  unsigned short* KVbf = (unsigned short*)R2;
  float* proj  = R2;
  unsigned short* h1bf = (unsigned short*)R2;
  float* proj2 = R3;
  float* xbt = R1;
  // Phase B aliases
  unsigned short* xnbf = (unsigned short*)R2;
  unsigned short* tnbf = (unsigned short*)(R2 + 4194304);
  unsigned short* qch = (unsigned short*)dof;
  float* kc  = R3;
  float* vc  = R3 + 2523136;
  unsigned short* ctxTbf = (unsigned short*)(R3 + 5046272);
  unsigned short* hstbf = (unsigned short*)(R3 + 6094848);
  unsigned short* xbbf  = (unsigned short*)(R3 + 8192000);
  float* eo  = R2 + 8421376;
  float* eo2 = eo + 65536;
  float* yb  = R2;
  // Phase C aliases
  unsigned short* g1bf = (unsigned short*)R2;
  float* y2 = dof;
  unsigned short* hst2bf = (unsigned short*)R3;

  // ---------- Phase A ----------
  cvt4_kernel<<<dim3(1024, 4), 256, 0, stream>>>(
      sa_in_w, w_sa_in, 786432, sa_out_w, w_sa_out, 262144,
      sa_l1_w, w_sa_l1, 524288, sa_l2_w, w_sa_l2, 524288);
  concat_src_kernel<<<10688, 256, 0, stream>>>(x, xf, emb, src, srcbf);
  // merged: Q-proj (EPI7, grid 4x128) + KV-proj (EPI0, grid 8x167)
  gemm_dual<7, true, 0, true><<<dim3(12, 167), 256, 0, stream>>>(
      srcbf, w_sa_in, sa_in_b, Qbf, M2, 512, 512, 512, 4, 128,
      srcbf, w_sa_in + (size_t)512 * 512, sa_in_b + 512, KVbf, M1, 512, 512, 1024);
  attn_mfma_kernel<<<dim3(2, BB * HH), 256, 0, stream>>>(Qbf, KVbf, Obf);
  gemm_bf<0, false><<<dim3(4, 128), 256, 0, stream>>>(
      Obf, w_sa_out, sa_out_b, proj, nullptr, M2, 512, 512, 512);
  ln_kernel<<<M2, 64, 0, stream>>>(src, proj, src, sa_n1_g, sa_n1_b, srcbf);
  gemm_bf<1, true><<<dim3(8, 128), 256, 0, stream>>>(
      srcbf, w_sa_l1, sa_l1_b, h1bf, nullptr, M2, 512, 512, 1024);
  gemm_bf<0, false><<<dim3(4, 128), 256, 0, stream>>>(
      h1bf, w_sa_l2, sa_l2_b, proj2, nullptr, M2, 1024, 1024, 512);
  cvt4_kernel<<<dim3(1024, 4), 256, 0, stream>>>(
      ca_q_w, w_ca_q, 262144, ca_k_w, w_ca_k, 262144,
      ca_v_w, w_ca_v, 262144, ca_so_w, w_ca_so, 262144);
  cvt4_kernel<<<dim3(1024, 4), 256, 0, stream>>>(
      ff_l1_w, w_ff_l1, 1048576, ff_l2_w, w_ff_l2, 1048576,
      ff_so_w, w_ff_so, 262144, nullptr, nullptr, 0);
  t2bln_res_kernel<<<M2, 64, 0, stream>>>(
      src, proj2, xnbf, sa_n2_g, sa_n2_b, ca_norm_g, ca_norm_b);

  // ---------- Phase B ----------
  gemm_bf<6, false><<<dim3(4, 128), 256, 0, stream>>>(
      xnbf, w_ca_q, ca_q_b, qch, nullptr, M2, 512, 512, 512);
  t2bln_kernel<<<BB * NN, 64, 0, stream>>>(xf, tnbf, ca_tnorm_g, ca_tnorm_b, NN);
  // merged: ca_k + ca_v (both grid 4x39, same A)
  gemm_dual<0, false, 0, false><<<dim3(8, 39), 256, 0, stream>>>(
      tnbf, w_ca_k, ca_k_b, kc, BB * NN, 512, 512, 512, 4, 39,
      tnbf, w_ca_v, ca_v_b, vc, BB * NN, 512, 512, 512);
  softmax_n_kernel<<<dim3(64, 2), 256, 0, stream>>>(kc);
  ctx_kernel<<<BB * HH, 256, 0, stream>>>(kc, vc, ctxTbf);
  gemm_se_kernel<<<dim3(16, 2), 256, 0, stream>>>(
      emb, ca_se_w, ca_se_b, eo, ff_se_w, ff_se_b, eo2);
  lin_y_mfma<<<BB * HH, 256, 0, stream>>>(qch, ctxTbf, yb);
  styl_kernel<<<M2, 64, 0, stream>>>(yb, eo, ca_sn_g, ca_sn_b, hstbf);
  gemm_bf<4, false><<<dim3(4, 128), 256, 0, stream>>>(
      hstbf, w_ca_so, ca_so_b, xbt, xbbf, M2, 512, 512, 512);

  // ---------- Phase C (N-split FFN: full-M dispatches) ----------
  gemm_bf<2, true><<<dim3(8, 128), 256, 0, stream>>>(
      xbbf, w_ff_l1, ff_l1_b, g1bf, nullptr, M2, 512, 512, 1024);
  gemm_bf<0, false><<<dim3(4, 128), 256, 0, stream>>>(
      g1bf, w_ff_l2, ff_l2_b, y2, nullptr, M2, 1024, 2048, 512);
  gemm_bf<2, true><<<dim3(8, 128), 256, 0, stream>>>(
      xbbf, w_ff_l1 + (size_t)1024 * 512, ff_l1_b + 1024, g1bf, nullptr, M2, 512, 512, 1024);
  gemm_bf<8, false><<<dim3(4, 128), 256, 0, stream>>>(
      g1bf, w_ff_l2 + 1024, ff_l2_b, y2, nullptr, M2, 1024, 2048, 512);
  styl_kernel<<<M2, 64, 0, stream>>>(y2, eo2, ff_sn_g, ff_sn_b, hst2bf);
  gemm_bf<5, false><<<dim3(4, 128), 256, 0, stream>>>(
      hst2bf, w_ff_so, ff_so_b, xbt, dof, M2, 512, 512, 512);
}